// Round 7
// baseline (2393.902 us; speedup 1.0000x reference)
//
#include <hip/hip_runtime.h>
#include <hip/hip_bf16.h>

typedef __hip_bfloat16 bf16;
typedef __bf16 bfv8 __attribute__((ext_vector_type(8)));
typedef float f32x4 __attribute__((ext_vector_type(4)));

#define BB 4
#define HH 128
#define WWI 128
#define NN 16384      // HH*WWI
#define CC 256
#define LL 4
#define NHEADS 8
#define DHD 32
#define GG 64
#define INNERC 256    // NHEADS*DHD
#define HIDD 1024
#define SPLIT 32      // split-K blocks per (b,h) in slice_st
#define SSP 16        // points per block in slice_softmax

__device__ __forceinline__ float b2f(bf16 x) { return __bfloat162float(x); }
__device__ __forceinline__ bf16 f2b(float x) { return __float2bfloat16(x); }
__device__ __forceinline__ float us2f(unsigned short v) {
  return __uint_as_float(((unsigned)v) << 16);
}
__device__ __forceinline__ unsigned short b2us(bf16 h) {
  union { bf16 b; unsigned short u; } c; c.b = h; return c.u;
}

// async global->LDS, 16B per lane; LDS dest = wave-uniform base + lane*16
__device__ __forceinline__ void async16(void* l, const void* g) {
  __builtin_amdgcn_global_load_lds(
      (const __attribute__((address_space(1))) void*)g,
      (__attribute__((address_space(3))) void*)l, 16, 0, 0);
}

__device__ __forceinline__ float wave_sum(float v) {
#pragma unroll
  for (int off = 32; off > 0; off >>= 1) v += __shfl_down(v, off, 64);
  return v;
}

__device__ __forceinline__ float gelu_exact(float x) {
  return 0.5f * x * (1.0f + erff(x * 0.70710678118654752f));
}

// ---------- batched transpose+cast: src fp32 [T][R][Cm] -> dst bf16 [T][Cm][R] ----------
__global__ void transpose_cast_kernel(const float* __restrict__ src, bf16* __restrict__ dst,
                                      int R, int Cm) {
  __shared__ float tile[32][33];
  int tb = blockIdx.z;
  const float* s = src + (size_t)tb * R * Cm;
  bf16* d = dst + (size_t)tb * R * Cm;
  int c0 = blockIdx.x * 32, r0 = blockIdx.y * 32;
  int tx = threadIdx.x & 31, ty = threadIdx.x >> 5;  // 32 x 8
  for (int rr = ty; rr < 32; rr += 8) {
    int r = r0 + rr, c = c0 + tx;
    tile[rr][tx] = (r < R && c < Cm) ? s[(size_t)r * Cm + c] : 0.f;
  }
  __syncthreads();
  for (int cc = ty; cc < 32; cc += 8) {
    int c = c0 + cc, r = r0 + tx;
    if (c < Cm && r < R) d[(size_t)c * R + r] = f2b(tile[tx][cc]);
  }
}

// ---------- LayerNorm (layer-0 ln1 only): one wave per point, float4, no LDS ----------
__global__ __launch_bounds__(256) void ln_kernel(const float* __restrict__ x,
                                                 const float* __restrict__ w,
                                                 const float* __restrict__ b,
                                                 bf16* __restrict__ out) {
  int wid = threadIdx.x >> 6, lane = threadIdx.x & 63;
  int p = blockIdx.x * 4 + wid;
  float4 v = ((const float4*)(x + (size_t)p * CC))[lane];
  float s = v.x + v.y + v.z + v.w;
  float sq = v.x * v.x + v.y * v.y + v.z * v.z + v.w * v.w;
#pragma unroll
  for (int off = 32; off > 0; off >>= 1) {
    s += __shfl_xor(s, off, 64);
    sq += __shfl_xor(sq, off, 64);
  }
  float mean = s * (1.0f / CC);
  float var = sq * (1.0f / CC) - mean * mean;
  float rstd = rsqrtf(var + 1e-5f);
  float4 wv = ((const float4*)w)[lane];
  float4 bv = ((const float4*)b)[lane];
  unsigned short o0 = b2us(f2b((v.x - mean) * rstd * wv.x + bv.x));
  unsigned short o1 = b2us(f2b((v.y - mean) * rstd * wv.y + bv.y));
  unsigned short o2 = b2us(f2b((v.z - mean) * rstd * wv.z + bv.z));
  unsigned short o3 = b2us(f2b((v.w - mean) * rstd * wv.w + bv.w));
  uint2 pk = make_uint2((unsigned)o0 | ((unsigned)o1 << 16),
                        (unsigned)o2 | ((unsigned)o3 << 16));
  ((uint2*)(out + (size_t)p * CC))[lane] = pk;
}

// ---------- 3x3 conv as implicit MFMA GEMM, v3 (unchanged) ----------
__global__ __launch_bounds__(512, 2) void conv_mfma_kernel(
    const bf16* __restrict__ xln, const bf16* __restrict__ wt,
    const float* __restrict__ bias, bf16* __restrict__ out,
    const float* __restrict__ zbuf) {
  __shared__ __align__(16) unsigned short As[4 * 130 * 64];   // 65 KiB (rows h0-1..h0+2)
  __shared__ __align__(16) unsigned short Bsm[2][256 * 64];   // 2 x 32 KiB
  int bid = blockIdx.x;
  bid = (bid & 7) * 32 + (bid >> 3);        // XCD swizzle (256 = 8*32, bijective)
  int h0 = (bid & 63) * 2;                  // output row pair
  int b = bid >> 6;
  int t = threadIdx.x, lane = t & 63, wid = t >> 6;
  int r = wid & 1;                          // output row within pair
  int wn = (wid >> 1) * 64;                 // oc quarter
  int l15 = lane & 15, l4 = lane >> 4;
  int wu = t & ~63;                         // wave-uniform thread base
  f32x4 acc[8][4];
#pragma unroll
  for (int mi = 0; mi < 8; ++mi)
#pragma unroll
    for (int ni = 0; ni < 4; ++ni) acc[mi][ni] = (f32x4){0.f, 0.f, 0.f, 0.f};
  const bf16* xbase = xln + (size_t)b * NN * CC;

  auto stageB = [&](int buf, int tap, int q) {
#pragma unroll
    for (int k = 0; k < 4; ++k) {
      int u = t + k * 512;
      int n = u >> 3, jp = u & 7, j = jp ^ (n & 7);
      async16(&Bsm[buf][(size_t)(wu + k * 512) * 8],
              wt + ((size_t)(tap * 256 + n)) * 256 + q * 64 + j * 8);
    }
  };

  for (int q = 0; q < 4; ++q) {             // 64-channel K chunks
#pragma unroll
    for (int k = 0; k < 8; ++k) {
      int u = t + k * 512;
      int jp = u & 7, pc = u >> 3;
      int ar = pc / 130, cl = pc - ar * 130;
      int j = jp ^ (cl & 7);
      int gr = h0 + ar - 1, gc = cl - 1;
      const void* src =
          ((unsigned)gr < 128u && (unsigned)gc < 128u)
              ? (const void*)(xbase + ((size_t)(gr * WWI + gc)) * CC + q * 64 + j * 8)
              : (const void*)zbuf;
      async16(&As[(size_t)(wu + k * 512) * 8], src);
    }
    if (t < 64) {
      int u = t + 4096;
      int jp = u & 7, pc = u >> 3;
      int ar = pc / 130, cl = pc - ar * 130;
      int j = jp ^ (cl & 7);
      int gr = h0 + ar - 1, gc = cl - 1;
      const void* src =
          ((unsigned)gr < 128u && (unsigned)gc < 128u)
              ? (const void*)(xbase + ((size_t)(gr * WWI + gc)) * CC + q * 64 + j * 8)
              : (const void*)zbuf;
      async16(&As[(size_t)4096 * 8], src);
    }
    if (q == 0) stageB(0, 0, 0);
    __syncthreads();

    for (int tap = 0; tap < 9; ++tap) {
      int cur = (q * 9 + tap) & 1;
      if (tap < 8)      stageB(cur ^ 1, tap + 1, q);
      else if (q < 3)   stageB(cur ^ 1, 0, q + 1);
      int ky = tap / 3, kx = tap - ky * 3;
      const unsigned short* Bc = Bsm[cur];
#pragma unroll
      for (int s = 0; s < 2; ++s) {
        bfv8 af[8], bfr[4];
#pragma unroll
        for (int mi = 0; mi < 8; ++mi) {
          int cl = mi * 16 + l15 + kx;
          af[mi] = *(const bfv8*)(&As[((size_t)((ky + r) * 130 + cl)) * 64 +
                                      (((s * 4 + l4) ^ (cl & 7)) << 3)]);
        }
#pragma unroll
        for (int ni = 0; ni < 4; ++ni) {
          int rn = wn + ni * 16 + l15;
          bfr[ni] = *(const bfv8*)(&Bc[(size_t)rn * 64 + (((s * 4 + l4) ^ (rn & 7)) << 3)]);
        }
#pragma unroll
        for (int mi = 0; mi < 8; ++mi)
#pragma unroll
          for (int ni = 0; ni < 4; ++ni)
            acc[mi][ni] = __builtin_amdgcn_mfma_f32_16x16x32_bf16(af[mi], bfr[ni], acc[mi][ni], 0, 0, 0);
      }
      __syncthreads();
    }
  }
  int colB = wn + l15;
  int rowB = l4 * 4;
#pragma unroll
  for (int ni = 0; ni < 4; ++ni) {
    int oc = colB + ni * 16;
    float bv = bias[oc];
#pragma unroll
    for (int mi = 0; mi < 8; ++mi) {
#pragma unroll
      for (int rr = 0; rr < 4; ++rr) {
        int pix = mi * 16 + rowB + rr;
        out[((size_t)(b * NN + (h0 + r) * WWI + pix)) * CC + oc] = f2b(acc[mi][ni][rr] + bv);
      }
    }
  }
}

// ---------- fused deslice GEMM + residual + LN2: 128m x 256n full-row blocks ----------
// fx += swb@wct + bo, then xln = ln2(fx). 512 thr / 8 waves (2 row-bands x 4 col-waves).
// Row stats via l15-shfl partials + 4 KiB LDS aliased into dead As. Eliminates ln2 pass.
__global__ __launch_bounds__(512) void gemm_ln_kernel(
    const bf16* __restrict__ A, const bf16* __restrict__ BT,
    const float* __restrict__ bias, float* __restrict__ fx,
    const float* __restrict__ lw, const float* __restrict__ lb,
    bf16* __restrict__ xout) {
  __shared__ __align__(16) unsigned short As[128 * 64];   // 16 KiB
  __shared__ __align__(16) unsigned short Bs[256 * 64];   // 32 KiB
  int z = blockIdx.y;
  const bf16* Aa = A + (size_t)z * NN * 512;
  const bf16* Ba = BT + (size_t)z * 256 * 512;
  size_t fb = (size_t)z * NN * 256;
  int m0 = blockIdx.x * 128;
  int t = threadIdx.x, lane = t & 63, wid = t >> 6;
  int wm = (wid & 1) * 64, wn = (wid >> 1) * 64;
  int l15 = lane & 15, q4 = lane >> 4;
  int wu = t & ~63;
  f32x4 acc[4][4];
#pragma unroll
  for (int mi = 0; mi < 4; ++mi)
#pragma unroll
    for (int ni = 0; ni < 4; ++ni) acc[mi][ni] = (f32x4){0.f, 0.f, 0.f, 0.f};

  for (int kb = 0; kb < 512; kb += 64) {
    __syncthreads();
#pragma unroll
    for (int i = 0; i < 2; ++i) {          // A: 128 rows x 64k = 1024 units
      int u = t + i * 512;
      int row = u >> 3, jp = u & 7, j = jp ^ (row & 7);
      async16(&As[(size_t)(wu + i * 512) * 8], Aa + (size_t)(m0 + row) * 512 + kb + j * 8);
    }
#pragma unroll
    for (int i = 0; i < 4; ++i) {          // B: 256 rows x 64k = 2048 units
      int u = t + i * 512;
      int n = u >> 3, jp = u & 7, j = jp ^ (n & 7);
      async16(&Bs[(size_t)(wu + i * 512) * 8], Ba + (size_t)n * 512 + kb + j * 8);
    }
    __syncthreads();
#pragma unroll
    for (int s = 0; s < 2; ++s) {
      int kgrp = s * 4 + q4;
      bfv8 af[4], bfr[4];
#pragma unroll
      for (int mi = 0; mi < 4; ++mi) {
        int row = wm + mi * 16 + l15;
        af[mi] = *(const bfv8*)(&As[(size_t)row * 64 + ((kgrp ^ (row & 7)) << 3)]);
      }
#pragma unroll
      for (int ni = 0; ni < 4; ++ni) {
        int n = wn + ni * 16 + l15;
        bfr[ni] = *(const bfv8*)(&Bs[(size_t)n * 64 + ((kgrp ^ (n & 7)) << 3)]);
      }
#pragma unroll
      for (int mi = 0; mi < 4; ++mi)
#pragma unroll
        for (int ni = 0; ni < 4; ++ni)
          acc[mi][ni] = __builtin_amdgcn_mfma_f32_16x16x32_bf16(af[mi], bfr[ni], acc[mi][ni], 0, 0, 0);
    }
  }
  // ---- epilogue: v = fx + acc + bias; stats; ln2 -> xout ----
  __syncthreads();                          // all waves past As/Bs reads; alias As
  float* rs = (float*)As;                   // [4][128]
  float* rq = rs + 512;                     // [4][128]
  int cw = wid >> 1;
  int colB = wn + l15;
  float bv[4], lwv[4], lbv[4];
#pragma unroll
  for (int ni = 0; ni < 4; ++ni) {
    bv[ni] = bias[colB + ni * 16];
    lwv[ni] = lw[colB + ni * 16];
    lbv[ni] = lb[colB + ni * 16];
  }
#pragma unroll
  for (int mi = 0; mi < 4; ++mi) {
#pragma unroll
    for (int r = 0; r < 4; ++r) {
      int row = m0 + wm + mi * 16 + q4 * 4 + r;
      float s = 0.f, sq = 0.f;
#pragma unroll
      for (int ni = 0; ni < 4; ++ni) {
        size_t idx = fb + (size_t)row * 256 + colB + ni * 16;
        float v = fx[idx] + acc[mi][ni][r] + bv[ni];
        fx[idx] = v;
        s += v; sq += v * v;
      }
#pragma unroll
      for (int off = 1; off < 16; off <<= 1) {
        s += __shfl_xor(s, off, 64);
        sq += __shfl_xor(sq, off, 64);
      }
      if (l15 == 0) {
        int lrow = wm + mi * 16 + q4 * 4 + r;
        rs[cw * 128 + lrow] = s;
        rq[cw * 128 + lrow] = sq;
      }
    }
  }
  __syncthreads();
#pragma unroll
  for (int mi = 0; mi < 4; ++mi) {
#pragma unroll
    for (int r = 0; r < 4; ++r) {
      int lrow = wm + mi * 16 + q4 * 4 + r;
      float tot = rs[lrow] + rs[128 + lrow] + rs[256 + lrow] + rs[384 + lrow];
      float totq = rq[lrow] + rq[128 + lrow] + rq[256 + lrow] + rq[384 + lrow];
      float mean = tot * (1.0f / CC);
      float var = totq * (1.0f / CC) - mean * mean;
      float rstd = rsqrtf(var + 1e-5f);
      int row = m0 + lrow;
#pragma unroll
      for (int ni = 0; ni < 4; ++ni) {
        size_t idx = fb + (size_t)row * 256 + colB + ni * 16;
        float v = fx[idx];                  // hot in L1/L2 (just stored)
        xout[idx] = f2b((v - mean) * rstd * lwv[ni] + lbv[ni]);
      }
    }
  }
}

// ---------- fused MLP + next-layer LN1: fx += gelu(xln@w1+b1)@w2+b2; xln = ln1'(fx) ----------
__global__ __launch_bounds__(512, 4) void mlp_fused_kernel(
    const bf16* __restrict__ xln, const bf16* __restrict__ w1t,
    const float* __restrict__ b1, const bf16* __restrict__ w2t,
    const float* __restrict__ b2, float* __restrict__ fx,
    const float* __restrict__ lnw, const float* __restrict__ lnb,
    bf16* __restrict__ xout) {
  __shared__ __align__(16) unsigned short As[64 * 256];   // 32 KiB (per-64 XOR swizzle)
  __shared__ __align__(16) bf16 Hs[64 * 128];             // 16 KiB
  __shared__ __align__(16) unsigned short Wb[256 * 64];   // 32 KiB weight staging
  int m0 = blockIdx.x * 64;
  int t = threadIdx.x, lane = t & 63, wid = t >> 6;       // wid 0..7
  int l15 = lane & 15, q4 = lane >> 4;
  int wm2 = (wid & 1) * 32, wn2 = (wid >> 1) * 32;
  int wm = (wid & 1) * 32, wn = (wid >> 1) * 64;

  const unsigned short* xg = (const unsigned short*)xln + (size_t)m0 * 256;
#pragma unroll
  for (int i = 0; i < 4; ++i) {
    int u = t + i * 512;
    int row = u >> 5, v = u & 31;
    int kb = v >> 3, jp = v & 7;
    uint4 val = ((const uint4*)xg)[u];
    ((uint4*)As)[row * 32 + kb * 8 + (jp ^ (row & 7))] = val;
  }

  f32x4 accO[2][4];
#pragma unroll
  for (int mi = 0; mi < 2; ++mi)
#pragma unroll
    for (int ni = 0; ni < 4; ++ni) accO[mi][ni] = (f32x4){0.f, 0.f, 0.f, 0.f};

  for (int j = 0; j < 8; ++j) {
    int hbase = j * 128;
    f32x4 acc2[2][2];
#pragma unroll
    for (int mi = 0; mi < 2; ++mi)
#pragma unroll
      for (int nj = 0; nj < 2; ++nj) acc2[mi][nj] = (f32x4){0.f, 0.f, 0.f, 0.f};
    for (int kb = 0; kb < 4; ++kb) {
      __syncthreads();
#pragma unroll
      for (int i = 0; i < 2; ++i) {
        int u = t + i * 512;
        int n = u >> 3, jp = u & 7;
        uint4 val = *(const uint4*)(w1t + (size_t)(hbase + n) * 256 + kb * 64 + jp * 8);
        ((uint4*)Wb)[n * 8 + (jp ^ (n & 7))] = val;
      }
      __syncthreads();
#pragma unroll
      for (int ks = 0; ks < 2; ++ks) {
        int kgrp = ks * 4 + q4;
        bfv8 af[2], bfr[2];
#pragma unroll
        for (int mi = 0; mi < 2; ++mi) {
          int row = wm2 + mi * 16 + l15;
          af[mi] = *(const bfv8*)(&As[row * 256 + kb * 64 + ((kgrp ^ (row & 7)) << 3)]);
        }
#pragma unroll
        for (int nj = 0; nj < 2; ++nj) {
          int n = wn2 + nj * 16 + l15;
          bfr[nj] = *(const bfv8*)(&Wb[n * 64 + ((kgrp ^ (n & 7)) << 3)]);
        }
#pragma unroll
        for (int mi = 0; mi < 2; ++mi)
#pragma unroll
          for (int nj = 0; nj < 2; ++nj)
            acc2[mi][nj] = __builtin_amdgcn_mfma_f32_16x16x32_bf16(af[mi], bfr[nj], acc2[mi][nj], 0, 0, 0);
      }
    }
#pragma unroll
    for (int nj = 0; nj < 2; ++nj) {
      int coln = wn2 + nj * 16 + l15;
      float bv = b1[hbase + coln];
      int half = coln >> 6, sub = (coln >> 3) & 7, lo = coln & 7;
#pragma unroll
      for (int mi = 0; mi < 2; ++mi) {
#pragma unroll
        for (int r = 0; r < 4; ++r) {
          int row = wm2 + mi * 16 + q4 * 4 + r;
          float v = acc2[mi][nj][r] + bv;
          Hs[row * 128 + half * 64 + (((sub ^ (row & 7)) << 3) + lo)] = f2b(gelu_exact(v));
        }
      }
    }
    for (int kb2 = 0; kb2 < 2; ++kb2) {
      __syncthreads();
#pragma unroll
      for (int i = 0; i < 4; ++i) {
        int u = t + i * 512;
        int n = u >> 3, jp = u & 7;
        uint4 val = *(const uint4*)(w2t + (size_t)n * 1024 + hbase + kb2 * 64 + jp * 8);
        ((uint4*)Wb)[n * 8 + (jp ^ (n & 7))] = val;
      }
      __syncthreads();
#pragma unroll
      for (int ks = 0; ks < 2; ++ks) {
        int kgrp = ks * 4 + q4;
        bfv8 af[2], bfr[4];
#pragma unroll
        for (int mi = 0; mi < 2; ++mi) {
          int row = wm + mi * 16 + l15;
          af[mi] = *(const bfv8*)(&Hs[row * 128 + kb2 * 64 + ((kgrp ^ (row & 7)) << 3)]);
        }
#pragma unroll
        for (int ni = 0; ni < 4; ++ni) {
          int n = wn + ni * 16 + l15;
          bfr[ni] = *(const bfv8*)(&Wb[n * 64 + ((kgrp ^ (n & 7)) << 3)]);
        }
#pragma unroll
        for (int mi = 0; mi < 2; ++mi)
#pragma unroll
          for (int ni = 0; ni < 4; ++ni)
            accO[mi][ni] = __builtin_amdgcn_mfma_f32_16x16x32_bf16(af[mi], bfr[ni], accO[mi][ni], 0, 0, 0);
      }
    }
  }
  // ---- epilogue: v = fx + accO + b2; write fx; fused ln1-next -> xout ----
  float* rs = (float*)As;                   // 2 KiB aliased into dead As
  float* rq = rs + 256;                     // [4][64] each
  int cw = wid >> 1;
  int colB = wn + l15;
  float bv[4], lwv[4], lbv[4];
#pragma unroll
  for (int ni = 0; ni < 4; ++ni) {
    bv[ni] = b2[colB + ni * 16];
    if (lnw) { lwv[ni] = lnw[colB + ni * 16]; lbv[ni] = lnb[colB + ni * 16]; }
  }
#pragma unroll
  for (int mi = 0; mi < 2; ++mi) {
#pragma unroll
    for (int r = 0; r < 4; ++r) {
      int row = m0 + wm + mi * 16 + q4 * 4 + r;
      float s = 0.f, sq = 0.f;
#pragma unroll
      for (int ni = 0; ni < 4; ++ni) {
        size_t idx = (size_t)row * 256 + colB + ni * 16;
        float v = fx[idx] + accO[mi][ni][r] + bv[ni];
        fx[idx] = v;
        s += v; sq += v * v;
      }
      if (lnw) {
#pragma unroll
        for (int off = 1; off < 16; off <<= 1) {
          s += __shfl_xor(s, off, 64);
          sq += __shfl_xor(sq, off, 64);
        }
        if (l15 == 0) {
          int lrow = wm + mi * 16 + q4 * 4 + r;
          rs[cw * 64 + lrow] = s;
          rq[cw * 64 + lrow] = sq;
        }
      }
    }
  }
  if (lnw) {
    __syncthreads();
#pragma unroll
    for (int mi = 0; mi < 2; ++mi) {
#pragma unroll
      for (int r = 0; r < 4; ++r) {
        int lrow = wm + mi * 16 + q4 * 4 + r;
        float tot = rs[lrow] + rs[64 + lrow] + rs[128 + lrow] + rs[192 + lrow];
        float totq = rq[lrow] + rq[64 + lrow] + rq[128 + lrow] + rq[192 + lrow];
        float mean = tot * (1.0f / CC);
        float var = totq * (1.0f / CC) - mean * mean;
        float rstd = rsqrtf(var + 1e-5f);
        int row = m0 + lrow;
#pragma unroll
        for (int ni = 0; ni < 4; ++ni) {
          size_t idx = (size_t)row * 256 + colB + ni * 16;
          float v = fx[idx];                // hot (just stored)
          xout[idx] = f2b((v - mean) * rstd * lwv[ni] + lbv[ni]);
        }
      }
    }
  }
}

// ---------- slice logits + softmax: slice weights in REGISTERS (lane g) ----------
__global__ __launch_bounds__(256) void slice_softmax_kernel(
    const bf16* __restrict__ xmid, const float* __restrict__ sw_w,
    const float* __restrict__ sw_b, const float* __restrict__ temp,
    bf16* __restrict__ swout) {
  __shared__ float xm[SSP][256];    // 16 KiB
  int p0 = blockIdx.x * SSP;
  int t = threadIdx.x;
  int g = t & 63, pq = t >> 6;
  float wreg[32];
#pragma unroll
  for (int d = 0; d < 32; ++d) wreg[d] = sw_w[d * 64 + g];   // coalesced per d
  float bg = sw_b[g];
  float rt[8];
#pragma unroll
  for (int h = 0; h < 8; ++h) rt[h] = 1.0f / fminf(fmaxf(temp[h], 0.1f), 5.0f);
  const unsigned short* xg = (const unsigned short*)xmid + (size_t)p0 * 256;
#pragma unroll
  for (int i2 = t; i2 < SSP * 32; i2 += 256) {
    uint4 v = ((const uint4*)xg)[i2];
    int p = i2 >> 5, c = (i2 & 31) << 3;
    xm[p][c + 0] = us2f((unsigned short)(v.x & 0xffff));
    xm[p][c + 1] = us2f((unsigned short)(v.x >> 16));
    xm[p][c + 2] = us2f((unsigned short)(v.y & 0xffff));
    xm[p][c + 3] = us2f((unsigned short)(v.y >> 16));
    xm[p][c + 4] = us2f((unsigned short)(v.z & 0xffff));
    xm[p][c + 5] = us2f((unsigned short)(v.z >> 16));
    xm[p][c + 6] = us2f((unsigned short)(v.w & 0xffff));
    xm[p][c + 7] = us2f((unsigned short)(v.w >> 16));
  }
  __syncthreads();
  for (int pp2 = 0; pp2 < SSP / 4; ++pp2) {
    int p = pp2 * 4 + pq;
#pragma unroll
    for (int h = 0; h < NHEADS; ++h) {
      float acc = bg;
      const float* xr = &xm[p][h * 32];
#pragma unroll
      for (int d = 0; d < 32; ++d) acc += xr[d] * wreg[d];
      float logit = acc * rt[h];
      float m = logit;
#pragma unroll
      for (int off = 32; off > 0; off >>= 1) m = fmaxf(m, __shfl_xor(m, off, 64));
      float e = __expf(logit - m);
      float s = e;
#pragma unroll
      for (int off = 32; off > 0; off >>= 1) s += __shfl_xor(s, off, 64);
      swout[(size_t)(p0 + p) * 512 + h * 64 + g] = f2b(e / s);
    }
  }
}

// ---------- slice reduce as split-K MFMA outer product (unchanged) ----------
__global__ __launch_bounds__(256) void slice_st_kernel(
    const bf16* __restrict__ fxmid, const bf16* __restrict__ sw,
    float* __restrict__ stp, float* __restrict__ normp) {
  __shared__ __align__(16) unsigned short sw_s[64 * 64];
  __shared__ __align__(16) unsigned short fx_s[32 * 64];
  __shared__ float npart[2][64];
  int split = blockIdx.x, h = blockIdx.y, b = blockIdx.z;
  int t = threadIdx.x, w = t >> 6, lane = t & 63;
  int l15 = lane & 15, q4 = lane >> 4;
  int ns0 = split * (NN / SPLIT);
  const int NT = (NN / SPLIT) / 64;
  f32x4 acc0 = {0.f, 0.f, 0.f, 0.f}, acc1 = {0.f, 0.f, 0.f, 0.f};
  float nacc = 0.f;
  const unsigned short* swg = (const unsigned short*)sw + (size_t)b * NN * 512 + h * 64;
  const unsigned short* fxg = (const unsigned short*)fxmid + (size_t)b * NN * 256 + h * 32;

  for (int kt = 0; kt < NT; ++kt) {
    int n0 = ns0 + kt * 64;
    __syncthreads();
    if (w < 2) {
      int g = lane;
#pragma unroll
      for (int i = 0; i < 4; ++i) {
        int j = w + 2 * i;
        const unsigned short* p = swg + (size_t)(n0 + j * 8) * 512 + g;
        unsigned short v0 = p[0],     v1 = p[512],  v2 = p[1024], v3 = p[1536];
        unsigned short v4 = p[2048],  v5 = p[2560], v6 = p[3072], v7 = p[3584];
        nacc += us2f(v0) + us2f(v1) + us2f(v2) + us2f(v3) +
                us2f(v4) + us2f(v5) + us2f(v6) + us2f(v7);
        uint4 pk = make_uint4((unsigned)v0 | ((unsigned)v1 << 16),
                              (unsigned)v2 | ((unsigned)v3 << 16),
                              (unsigned)v4 | ((unsigned)v5 << 16),
                              (unsigned)v6 | ((unsigned)v7 << 16));
        ((uint4*)sw_s)[g * 8 + (j ^ (g & 7))] = pk;
      }
    } else {
      int d = lane & 31, nh = lane >> 5, w3 = w - 2;
#pragma unroll
      for (int i = 0; i < 2; ++i) {
        int nbase = (w3 * 2 + i) * 16 + nh * 8;
        const unsigned short* p = fxg + (size_t)(n0 + nbase) * 256 + d;
        unsigned short v0 = p[0],    v1 = p[256],  v2 = p[512],  v3 = p[768];
        unsigned short v4 = p[1024], v5 = p[1280], v6 = p[1536], v7 = p[1792];
        uint4 pk = make_uint4((unsigned)v0 | ((unsigned)v1 << 16),
                              (unsigned)v2 | ((unsigned)v3 << 16),
                              (unsigned)v4 | ((unsigned)v5 << 16),
                              (unsigned)v6 | ((unsigned)v7 << 16));
        int u = nbase >> 3;
        ((uint4*)fx_s)[d * 8 + (u ^ (d & 7))] = pk;
      }
    }
    __syncthreads();
    int gg = w * 16 + l15;
    int d0 = l15, d1 = 16 + l15;
#pragma unroll
    for (int ks = 0; ks < 2; ++ks) {
      bfv8 af  = ((const bfv8*)sw_s)[gg * 8 + ((ks * 4 + q4) ^ (gg & 7))];
      bfv8 bf0 = ((const bfv8*)fx_s)[d0 * 8 + ((ks * 4 + q4) ^ (d0 & 7))];
      bfv8 bf1 = ((const bfv8*)fx_s)[d1 * 8 + ((ks * 4 + q4) ^ (d1 & 7))];
      acc0 = __builtin_amdgcn_mfma_f32_16x16x32_bf16(af, bf0, acc0, 0, 0, 0);
      acc1 = __builtin_amdgcn_mfma_f32_16x16x32_bf16(af, bf1, acc1, 0, 0, 0);
    }
  }
  if (w < 2) npart[w][lane] = nacc;
  __syncthreads();
  int bh = b * NHEADS + h;
  if (t < 64) normp[(size_t)split * (BB * NHEADS * GG) + bh * 64 + t] = npart[0][t] + npart[1][t];
  size_t base = ((size_t)split * (BB * NHEADS * GG) + bh * 64) * 32;
#pragma unroll
  for (int r = 0; r < 4; ++r) {
    int g = w * 16 + q4 * 4 + r;
    stp[base + (size_t)g * 32 + l15] = acc0[r];
    stp[base + (size_t)g * 32 + 16 + l15] = acc1[r];
  }
}

// ---------- fused attention + wo-column projection per (b,h) ----------
__global__ __launch_bounds__(256) void attn_wc_kernel(
    const float* __restrict__ stp, const float* __restrict__ normp,
    const float* __restrict__ wq, const float* __restrict__ wk,
    const float* __restrict__ wv, const float* __restrict__ wo,
    bf16* __restrict__ wct) {
  __shared__ float wqs[32 * 32], wks[32 * 32], wvs[32 * 32];
  __shared__ float st[GG][DHD + 1];
  __shared__ float qq[GG][DHD + 1], kk[GG][DHD + 1], vv[GG][DHD + 1];
  __shared__ float pm[GG][GG + 1];
  __shared__ float nrm[GG];
  int bh = blockIdx.x;
  int h2 = bh & 7, bq = bh >> 3;
  int t = threadIdx.x;
  ((float4*)wqs)[t] = ((const float4*)wq)[t];
  ((float4*)wks)[t] = ((const float4*)wk)[t];
  ((float4*)wvs)[t] = ((const float4*)wv)[t];
  float wol[DHD];                           // wo column c = t, loaded early
#pragma unroll
  for (int d = 0; d < DHD; ++d) wol[d] = wo[(size_t)(h2 * DHD + d) * CC + t];
  if (t < 64) {
    float ns = 0.f;
    for (int s = 0; s < SPLIT; ++s) ns += normp[(size_t)s * (BB * NHEADS * GG) + bh * 64 + t];
    nrm[t] = 1.0f / (ns + 1e-5f);
  }
  __syncthreads();
#pragma unroll
  for (int i = 0; i < 8; ++i) {
    int idx = t + i * 256;
    int g = idx >> 5, d = idx & 31;
    float a = 0.f;
    for (int s = 0; s < SPLIT; ++s)
      a += stp[((size_t)s * (BB * NHEADS * GG) + bh * 64 + g) * 32 + d];
    st[g][d] = a * nrm[g];
  }
  __syncthreads();
#pragma unroll
  for (int i = 0; i < 8; ++i) {
    int idx = t + i * 256;
    int g = idx >> 5, d = idx & 31;
    float aq = 0.f, ak = 0.f, av = 0.f;
#pragma unroll
    for (int c = 0; c < 32; ++c) {
      float sv = st[g][c];
      aq += sv * wqs[c * 32 + d];
      ak += sv * wks[c * 32 + d];
      av += sv * wvs[c * 32 + d];
    }
    qq[g][d] = aq; kk[g][d] = ak; vv[g][d] = av;
  }
  __syncthreads();
  {
    int g = t >> 2, sub = t & 3;
    float sc[16];
    float m = -1e30f;
    const float scale = 0.17677669529663687f;
#pragma unroll
    for (int jj = 0; jj < 16; ++jj) {
      int j = sub * 16 + jj;
      float a = 0.f;
#pragma unroll
      for (int d = 0; d < 32; ++d) a += qq[g][d] * kk[j][d];
      a *= scale;
      sc[jj] = a;
      m = fmaxf(m, a);
    }
    m = fmaxf(m, __shfl_xor(m, 1, 64));
    m = fmaxf(m, __shfl_xor(m, 2, 64));
    float ssum = 0.f;
#pragma unroll
    for (int jj = 0; jj < 16; ++jj) { sc[jj] = __expf(sc[jj] - m); ssum += sc[jj]; }
    ssum += __shfl_xor(ssum, 1, 64);
    ssum += __shfl_xor(ssum, 2, 64);
    float rs = 1.0f / ssum;
#pragma unroll
    for (int jj = 0; jj < 16; ++jj) pm[g][sub * 16 + jj] = sc[jj] * rs;
  }
  __syncthreads();
#pragma unroll
  for (int i = 0; i < 8; ++i) {            // PV -> qq (Q dead after scores)
    int idx = t + i * 256;
    int g = idx >> 5, d = idx & 31;
    float a = 0.f;
#pragma unroll
    for (int j = 0; j < GG; ++j) a += pm[g][j] * vv[j][d];
    qq[g][d] = a;
  }
  __syncthreads();
  // wc: wct[b][c][h*64+g] = sum_d ot[g][d] * wo[h*32+d][c], c = t
  bf16* dst = wct + ((size_t)bq * CC + t) * (NHEADS * GG) + h2 * GG;
#pragma unroll 4
  for (int g = 0; g < GG; ++g) {
    float a = 0.f;
#pragma unroll
    for (int d = 0; d < DHD; ++d) a += wol[d] * qq[g][d];
    dst[g] = f2b(a);
  }
}

// ---------- final LN3 + head: one wave per point, float4, no LDS/barrier ----------
__global__ __launch_bounds__(256) void head_kernel(const float* __restrict__ fx,
                                                   const float* __restrict__ w,
                                                   const float* __restrict__ b,
                                                   const float* __restrict__ wout,
                                                   const float* __restrict__ bout,
                                                   float* __restrict__ out) {
  int wid = threadIdx.x >> 6, lane = threadIdx.x & 63;
  int p = blockIdx.x * 4 + wid;
  float4 v = ((const float4*)(fx + (size_t)p * CC))[lane];
  float s = v.x + v.y + v.z + v.w;
  float sq = v.x * v.x + v.y * v.y + v.z * v.z + v.w * v.w;
#pragma unroll
  for (int off = 32; off > 0; off >>= 1) {
    s += __shfl_xor(s, off, 64);
    sq += __shfl_xor(sq, off, 64);
  }
  float mean = s * (1.0f / CC);
  float var = sq * (1.0f / CC) - mean * mean;
  float rstd = rsqrtf(var + 1e-5f);
  float4 wv = ((const float4*)w)[lane];
  float4 bv = ((const float4*)b)[lane];
  float xn0 = (v.x - mean) * rstd * wv.x + bv.x;
  float xn1 = (v.y - mean) * rstd * wv.y + bv.y;
  float xn2 = (v.z - mean) * rstd * wv.z + bv.z;
  float xn3 = (v.w - mean) * rstd * wv.w + bv.w;
  float4 w0 = ((const float4*)wout)[lane * 4 + 0];
  float4 w1 = ((const float4*)wout)[lane * 4 + 1];
  float4 w2 = ((const float4*)wout)[lane * 4 + 2];
  float4 w3 = ((const float4*)wout)[lane * 4 + 3];
  float4 o;
  o.x = xn0 * w0.x + xn1 * w1.x + xn2 * w2.x + xn3 * w3.x;
  o.y = xn0 * w0.y + xn1 * w1.y + xn2 * w2.y + xn3 * w3.y;
  o.z = xn0 * w0.z + xn1 * w1.z + xn2 * w2.z + xn3 * w3.z;
  o.w = xn0 * w0.w + xn1 * w1.w + xn2 * w2.w + xn3 * w3.w;
#pragma unroll
  for (int off = 32; off > 0; off >>= 1) {
    o.x += __shfl_xor(o.x, off, 64);
    o.y += __shfl_xor(o.y, off, 64);
    o.z += __shfl_xor(o.z, off, 64);
    o.w += __shfl_xor(o.w, off, 64);
  }
  if (lane == 0) {
    float4 bo4 = *((const float4*)bout);
    float4 r;
    r.x = o.x + bo4.x; r.y = o.y + bo4.y; r.z = o.z + bo4.z; r.w = o.w + bo4.w;
    ((float4*)out)[p] = r;
  }
}

extern "C" void kernel_launch(void* const* d_in, const int* in_sizes, int n_in,
                              void* d_out, int out_size, void* d_ws, size_t ws_size,
                              hipStream_t stream) {
  const float* fx_in      = (const float*)d_in[0];
  const float* ln1_w      = (const float*)d_in[1];
  const float* ln1_b      = (const float*)d_in[2];
  const float* convx_w    = (const float*)d_in[3];
  const float* convx_b    = (const float*)d_in[4];
  const float* convfx_w   = (const float*)d_in[5];
  const float* convfx_b   = (const float*)d_in[6];
  const float* slice_w    = (const float*)d_in[7];
  const float* slice_b    = (const float*)d_in[8];
  const float* temperature= (const float*)d_in[9];
  const float* wq         = (const float*)d_in[10];
  const float* wk         = (const float*)d_in[11];
  const float* wv         = (const float*)d_in[12];
  const float* wo         = (const float*)d_in[13];
  const float* bo         = (const float*)d_in[14];
  const float* ln2_w      = (const float*)d_in[15];
  const float* ln2_b      = (const float*)d_in[16];
  const float* w1         = (const float*)d_in[17];
  const float* b1         = (const float*)d_in[18];
  const float* w2         = (const float*)d_in[19];
  const float* b2         = (const float*)d_in[20];
  const float* ln3_w      = (const float*)d_in[21];
  const float* ln3_b      = (const float*)d_in[22];
  const float* w_out      = (const float*)d_in[23];
  const float* b_out      = (const float*)d_in[24];
  float* out = (float*)d_out;

  char* ws = (char*)d_ws;
  size_t off = 0;
  auto alloc = [&](size_t bytes) -> void* {
    void* p = ws + off;
    off += (bytes + 255) & ~(size_t)255;
    return p;
  };
  float* fx32  = (float*)alloc((size_t)BB * NN * CC * 4);    // 64 MiB
  bf16* xln    = (bf16*)alloc((size_t)BB * NN * CC * 2);     // 32 MiB
  char* uni    = (char*)alloc((size_t)BB * NN * 512 * 2 * 2);// xmid/fxmid/swb region
  bf16* xmid   = (bf16*)uni;
  bf16* fxmid  = (bf16*)(uni + (size_t)BB * NN * INNERC * 2);
  bf16* swb    = (bf16*)(uni + (size_t)2 * BB * NN * INNERC * 2);
  float* stp   = (float*)uni;                                // 8 MiB (aliases dead xmid)
  float* normp = (float*)(uni + (size_t)SPLIT * BB * NHEADS * GG * DHD * 4);
  bf16* wtx    = (bf16*)alloc((size_t)LL * 9 * CC * INNERC * 2);
  bf16* wtfx   = (bf16*)alloc((size_t)LL * 9 * CC * INNERC * 2);
  bf16* w1t    = (bf16*)alloc((size_t)LL * CC * HIDD * 2);
  bf16* w2t    = (bf16*)alloc((size_t)LL * HIDD * CC * 2);
  bf16* wct    = (bf16*)alloc((size_t)BB * CC * NHEADS * GG * 2);   // 1 MiB
  float* zbuf  = (float*)alloc(256);                          // zero pad for conv halo
  (void)ws_size; (void)in_sizes; (void)n_in; (void)out_size;

  hipMemsetAsync(zbuf, 0, 256, stream);

  transpose_cast_kernel<<<dim3(8, 8, LL * 9), 256, 0, stream>>>(convx_w, wtx, CC, INNERC);
  transpose_cast_kernel<<<dim3(8, 8, LL * 9), 256, 0, stream>>>(convfx_w, wtfx, CC, INNERC);
  transpose_cast_kernel<<<dim3(32, 8, LL), 256, 0, stream>>>(w1, w1t, CC, HIDD);
  transpose_cast_kernel<<<dim3(8, 32, LL), 256, 0, stream>>>(w2, w2t, HIDD, CC);

  hipMemcpyAsync(fx32, fx_in, (size_t)BB * NN * CC * sizeof(float),
                 hipMemcpyDeviceToDevice, stream);

  const int M = BB * NN;  // 65536
  // layer-0 ln1 (subsequent ln1 are fused into mlp epilogues)
  ln_kernel<<<M / 4, 256, 0, stream>>>(fx32, ln1_w, ln1_b, xln);
  for (int i = 0; i < LL; ++i) {
    conv_mfma_kernel<<<BB * HH / 2, 512, 0, stream>>>(
        xln, wtfx + (size_t)i * 9 * CC * INNERC, convfx_b + i * INNERC, fxmid,
        (const float*)zbuf);
    conv_mfma_kernel<<<BB * HH / 2, 512, 0, stream>>>(
        xln, wtx + (size_t)i * 9 * CC * INNERC, convx_b + i * INNERC, xmid,
        (const float*)zbuf);
    slice_softmax_kernel<<<M / SSP, 256, 0, stream>>>(
        xmid, slice_w + i * DHD * GG, slice_b + i * GG, temperature + i * NHEADS, swb);
    slice_st_kernel<<<dim3(SPLIT, NHEADS, BB), 256, 0, stream>>>(fxmid, swb, stp, normp);
    attn_wc_kernel<<<BB * NHEADS, 256, 0, stream>>>(
        stp, normp, wq + i * DHD * DHD, wk + i * DHD * DHD, wv + i * DHD * DHD,
        wo + (size_t)i * INNERC * CC, wct);
    // fx += sw @ Wc + bo, then xln = ln2(fx)  (deslice + wo-proj + residual + LN fused)
    gemm_ln_kernel<<<dim3(NN / 128, BB), 512, 0, stream>>>(
        swb, wct, bo + i * CC, fx32, ln2_w + i * CC, ln2_b + i * CC, xln);
    // fx += mlp(xln); xln = ln1[i+1](fx) fused (skipped for last layer)
    const float* nlw = (i < LL - 1) ? ln1_w + (i + 1) * CC : nullptr;
    const float* nlb = (i < LL - 1) ? ln1_b + (i + 1) * CC : nullptr;
    mlp_fused_kernel<<<M / 64, 512, 0, stream>>>(
        xln, w1t + (size_t)i * CC * HIDD, b1 + i * HIDD,
        w2t + (size_t)i * HIDD * CC, b2 + i * CC, fx32, nlw, nlb, xln);
  }
  head_kernel<<<M / 4, 256, 0, stream>>>(fx32, ln3_w, ln3_b, w_out, b_out, out);
}

// Round 10
// 2251.639 us; speedup vs baseline: 1.0632x; 1.0632x over previous
//
#include <hip/hip_runtime.h>
#include <hip/hip_bf16.h>

typedef __hip_bfloat16 bf16;
typedef __bf16 bfv8 __attribute__((ext_vector_type(8)));
typedef float f32x4 __attribute__((ext_vector_type(4)));

#define BB 4
#define HH 128
#define WWI 128
#define NN 16384      // HH*WWI
#define CC 256
#define LL 4
#define NHEADS 8
#define DHD 32
#define GG 64
#define INNERC 256    // NHEADS*DHD
#define HIDD 1024
#define SPLIT 32      // split-K blocks per (b,h) in slice_st
#define SSP 16        // points per block in slice_softmax

__device__ __forceinline__ float b2f(bf16 x) { return __bfloat162float(x); }
__device__ __forceinline__ bf16 f2b(float x) { return __float2bfloat16(x); }
__device__ __forceinline__ float us2f(unsigned short v) {
  return __uint_as_float(((unsigned)v) << 16);
}
__device__ __forceinline__ unsigned short b2us(bf16 h) {
  union { bf16 b; unsigned short u; } c; c.b = h; return c.u;
}

// async global->LDS, 16B per lane; LDS dest = wave-uniform base + lane*16
__device__ __forceinline__ void async16(void* l, const void* g) {
  __builtin_amdgcn_global_load_lds(
      (const __attribute__((address_space(1))) void*)g,
      (__attribute__((address_space(3))) void*)l, 16, 0, 0);
}

__device__ __forceinline__ float wave_sum(float v) {
#pragma unroll
  for (int off = 32; off > 0; off >>= 1) v += __shfl_down(v, off, 64);
  return v;
}

__device__ __forceinline__ float gelu_exact(float x) {
  return 0.5f * x * (1.0f + erff(x * 0.70710678118654752f));
}

// ---------- batched transpose+cast: src fp32 [T][R][Cm] -> dst bf16 [T][Cm][R] ----------
__global__ void transpose_cast_kernel(const float* __restrict__ src, bf16* __restrict__ dst,
                                      int R, int Cm) {
  __shared__ float tile[32][33];
  int tb = blockIdx.z;
  const float* s = src + (size_t)tb * R * Cm;
  bf16* d = dst + (size_t)tb * R * Cm;
  int c0 = blockIdx.x * 32, r0 = blockIdx.y * 32;
  int tx = threadIdx.x & 31, ty = threadIdx.x >> 5;  // 32 x 8
  for (int rr = ty; rr < 32; rr += 8) {
    int r = r0 + rr, c = c0 + tx;
    tile[rr][tx] = (r < R && c < Cm) ? s[(size_t)r * Cm + c] : 0.f;
  }
  __syncthreads();
  for (int cc = ty; cc < 32; cc += 8) {
    int c = c0 + cc, r = r0 + tx;
    if (c < Cm && r < R) d[(size_t)c * R + r] = f2b(tile[tx][cc]);
  }
}

// ---------- LayerNorm (ln1): one wave per point, float4 loads, no LDS/barrier ----------
__global__ __launch_bounds__(256) void ln_kernel(const float* __restrict__ x,
                                                 const float* __restrict__ w,
                                                 const float* __restrict__ b,
                                                 bf16* __restrict__ out) {
  int wid = threadIdx.x >> 6, lane = threadIdx.x & 63;
  int p = blockIdx.x * 4 + wid;
  float4 v = ((const float4*)(x + (size_t)p * CC))[lane];
  float s = v.x + v.y + v.z + v.w;
  float sq = v.x * v.x + v.y * v.y + v.z * v.z + v.w * v.w;
#pragma unroll
  for (int off = 32; off > 0; off >>= 1) {
    s += __shfl_xor(s, off, 64);
    sq += __shfl_xor(sq, off, 64);
  }
  float mean = s * (1.0f / CC);
  float var = sq * (1.0f / CC) - mean * mean;
  float rstd = rsqrtf(var + 1e-5f);
  float4 wv = ((const float4*)w)[lane];
  float4 bv = ((const float4*)b)[lane];
  unsigned short o0 = b2us(f2b((v.x - mean) * rstd * wv.x + bv.x));
  unsigned short o1 = b2us(f2b((v.y - mean) * rstd * wv.y + bv.y));
  unsigned short o2 = b2us(f2b((v.z - mean) * rstd * wv.z + bv.z));
  unsigned short o3 = b2us(f2b((v.w - mean) * rstd * wv.w + bv.w));
  uint2 pk = make_uint2((unsigned)o0 | ((unsigned)o1 << 16),
                        (unsigned)o2 | ((unsigned)o3 << 16));
  ((uint2*)(out + (size_t)p * CC))[lane] = pk;
}

// ---------- 3x3 conv as implicit MFMA GEMM, v3 (unchanged) ----------
__global__ __launch_bounds__(512, 2) void conv_mfma_kernel(
    const bf16* __restrict__ xln, const bf16* __restrict__ wt,
    const float* __restrict__ bias, bf16* __restrict__ out,
    const float* __restrict__ zbuf) {
  __shared__ __align__(16) unsigned short As[4 * 130 * 64];   // 65 KiB (rows h0-1..h0+2)
  __shared__ __align__(16) unsigned short Bsm[2][256 * 64];   // 2 x 32 KiB
  int bid = blockIdx.x;
  bid = (bid & 7) * 32 + (bid >> 3);        // XCD swizzle (256 = 8*32, bijective)
  int h0 = (bid & 63) * 2;                  // output row pair
  int b = bid >> 6;
  int t = threadIdx.x, lane = t & 63, wid = t >> 6;
  int r = wid & 1;                          // output row within pair
  int wn = (wid >> 1) * 64;                 // oc quarter
  int l15 = lane & 15, l4 = lane >> 4;
  int wu = t & ~63;                         // wave-uniform thread base
  f32x4 acc[8][4];
#pragma unroll
  for (int mi = 0; mi < 8; ++mi)
#pragma unroll
    for (int ni = 0; ni < 4; ++ni) acc[mi][ni] = (f32x4){0.f, 0.f, 0.f, 0.f};
  const bf16* xbase = xln + (size_t)b * NN * CC;

  auto stageB = [&](int buf, int tap, int q) {
#pragma unroll
    for (int k = 0; k < 4; ++k) {
      int u = t + k * 512;
      int n = u >> 3, jp = u & 7, j = jp ^ (n & 7);
      async16(&Bsm[buf][(size_t)(wu + k * 512) * 8],
              wt + ((size_t)(tap * 256 + n)) * 256 + q * 64 + j * 8);
    }
  };

  for (int q = 0; q < 4; ++q) {             // 64-channel K chunks
#pragma unroll
    for (int k = 0; k < 8; ++k) {
      int u = t + k * 512;
      int jp = u & 7, pc = u >> 3;
      int ar = pc / 130, cl = pc - ar * 130;
      int j = jp ^ (cl & 7);
      int gr = h0 + ar - 1, gc = cl - 1;
      const void* src =
          ((unsigned)gr < 128u && (unsigned)gc < 128u)
              ? (const void*)(xbase + ((size_t)(gr * WWI + gc)) * CC + q * 64 + j * 8)
              : (const void*)zbuf;
      async16(&As[(size_t)(wu + k * 512) * 8], src);
    }
    if (t < 64) {
      int u = t + 4096;
      int jp = u & 7, pc = u >> 3;
      int ar = pc / 130, cl = pc - ar * 130;
      int j = jp ^ (cl & 7);
      int gr = h0 + ar - 1, gc = cl - 1;
      const void* src =
          ((unsigned)gr < 128u && (unsigned)gc < 128u)
              ? (const void*)(xbase + ((size_t)(gr * WWI + gc)) * CC + q * 64 + j * 8)
              : (const void*)zbuf;
      async16(&As[(size_t)4096 * 8], src);
    }
    if (q == 0) stageB(0, 0, 0);
    __syncthreads();

    for (int tap = 0; tap < 9; ++tap) {
      int cur = (q * 9 + tap) & 1;
      if (tap < 8)      stageB(cur ^ 1, tap + 1, q);
      else if (q < 3)   stageB(cur ^ 1, 0, q + 1);
      int ky = tap / 3, kx = tap - ky * 3;
      const unsigned short* Bc = Bsm[cur];
#pragma unroll
      for (int s = 0; s < 2; ++s) {
        bfv8 af[8], bfr[4];
#pragma unroll
        for (int mi = 0; mi < 8; ++mi) {
          int cl = mi * 16 + l15 + kx;
          af[mi] = *(const bfv8*)(&As[((size_t)((ky + r) * 130 + cl)) * 64 +
                                      (((s * 4 + l4) ^ (cl & 7)) << 3)]);
        }
#pragma unroll
        for (int ni = 0; ni < 4; ++ni) {
          int rn = wn + ni * 16 + l15;
          bfr[ni] = *(const bfv8*)(&Bc[(size_t)rn * 64 + (((s * 4 + l4) ^ (rn & 7)) << 3)]);
        }
#pragma unroll
        for (int mi = 0; mi < 8; ++mi)
#pragma unroll
          for (int ni = 0; ni < 4; ++ni)
            acc[mi][ni] = __builtin_amdgcn_mfma_f32_16x16x32_bf16(af[mi], bfr[ni], acc[mi][ni], 0, 0, 0);
      }
      __syncthreads();
    }
  }
  int colB = wn + l15;
  int rowB = l4 * 4;
#pragma unroll
  for (int ni = 0; ni < 4; ++ni) {
    int oc = colB + ni * 16;
    float bv = bias[oc];
#pragma unroll
    for (int mi = 0; mi < 8; ++mi) {
#pragma unroll
      for (int rr = 0; rr < 4; ++rr) {
        int pix = mi * 16 + rowB + rr;
        out[((size_t)(b * NN + (h0 + r) * WWI + pix)) * CC + oc] = f2b(acc[mi][ni][rr] + bv);
      }
    }
  }
}

// ---------- fused deslice GEMM + residual + LN2 (kept from r7) ----------
__global__ __launch_bounds__(512) void gemm_ln_kernel(
    const bf16* __restrict__ A, const bf16* __restrict__ BT,
    const float* __restrict__ bias, float* __restrict__ fx,
    const float* __restrict__ lw, const float* __restrict__ lb,
    bf16* __restrict__ xout) {
  __shared__ __align__(16) unsigned short As[128 * 64];   // 16 KiB
  __shared__ __align__(16) unsigned short Bs[256 * 64];   // 32 KiB
  int z = blockIdx.y;
  const bf16* Aa = A + (size_t)z * NN * 512;
  const bf16* Ba = BT + (size_t)z * 256 * 512;
  size_t fb = (size_t)z * NN * 256;
  int m0 = blockIdx.x * 128;
  int t = threadIdx.x, lane = t & 63, wid = t >> 6;
  int wm = (wid & 1) * 64, wn = (wid >> 1) * 64;
  int l15 = lane & 15, q4 = lane >> 4;
  int wu = t & ~63;
  f32x4 acc[4][4];
#pragma unroll
  for (int mi = 0; mi < 4; ++mi)
#pragma unroll
    for (int ni = 0; ni < 4; ++ni) acc[mi][ni] = (f32x4){0.f, 0.f, 0.f, 0.f};

  for (int kb = 0; kb < 512; kb += 64) {
    __syncthreads();
#pragma unroll
    for (int i = 0; i < 2; ++i) {          // A: 128 rows x 64k = 1024 units
      int u = t + i * 512;
      int row = u >> 3, jp = u & 7, j = jp ^ (row & 7);
      async16(&As[(size_t)(wu + i * 512) * 8], Aa + (size_t)(m0 + row) * 512 + kb + j * 8);
    }
#pragma unroll
    for (int i = 0; i < 4; ++i) {          // B: 256 rows x 64k = 2048 units
      int u = t + i * 512;
      int n = u >> 3, jp = u & 7, j = jp ^ (n & 7);
      async16(&Bs[(size_t)(wu + i * 512) * 8], Ba + (size_t)n * 512 + kb + j * 8);
    }
    __syncthreads();
#pragma unroll
    for (int s = 0; s < 2; ++s) {
      int kgrp = s * 4 + q4;
      bfv8 af[4], bfr[4];
#pragma unroll
      for (int mi = 0; mi < 4; ++mi) {
        int row = wm + mi * 16 + l15;
        af[mi] = *(const bfv8*)(&As[(size_t)row * 64 + ((kgrp ^ (row & 7)) << 3)]);
      }
#pragma unroll
      for (int ni = 0; ni < 4; ++ni) {
        int n = wn + ni * 16 + l15;
        bfr[ni] = *(const bfv8*)(&Bs[(size_t)n * 64 + ((kgrp ^ (n & 7)) << 3)]);
      }
#pragma unroll
      for (int mi = 0; mi < 4; ++mi)
#pragma unroll
        for (int ni = 0; ni < 4; ++ni)
          acc[mi][ni] = __builtin_amdgcn_mfma_f32_16x16x32_bf16(af[mi], bfr[ni], acc[mi][ni], 0, 0, 0);
    }
  }
  // ---- epilogue: v = fx + acc + bias; stats; ln2 -> xout ----
  __syncthreads();                          // all waves past As/Bs reads; alias As
  float* rs = (float*)As;                   // [4][128]
  float* rq = rs + 512;                     // [4][128]
  int cw = wid >> 1;
  int colB = wn + l15;
  float bv[4], lwv[4], lbv[4];
#pragma unroll
  for (int ni = 0; ni < 4; ++ni) {
    bv[ni] = bias[colB + ni * 16];
    lwv[ni] = lw[colB + ni * 16];
    lbv[ni] = lb[colB + ni * 16];
  }
  float vkeep[4][4][4];
#pragma unroll
  for (int mi = 0; mi < 4; ++mi) {
#pragma unroll
    for (int r = 0; r < 4; ++r) {
      int row = m0 + wm + mi * 16 + q4 * 4 + r;
      float s = 0.f, sq = 0.f;
#pragma unroll
      for (int ni = 0; ni < 4; ++ni) {
        size_t idx = fb + (size_t)row * 256 + colB + ni * 16;
        float v = fx[idx] + acc[mi][ni][r] + bv[ni];
        fx[idx] = v;
        vkeep[mi][r][ni] = v;
        s += v; sq += v * v;
      }
#pragma unroll
      for (int off = 1; off < 16; off <<= 1) {
        s += __shfl_xor(s, off, 64);
        sq += __shfl_xor(sq, off, 64);
      }
      if (l15 == 0) {
        int lrow = wm + mi * 16 + q4 * 4 + r;
        rs[cw * 128 + lrow] = s;
        rq[cw * 128 + lrow] = sq;
      }
    }
  }
  __syncthreads();
#pragma unroll
  for (int mi = 0; mi < 4; ++mi) {
#pragma unroll
    for (int r = 0; r < 4; ++r) {
      int lrow = wm + mi * 16 + q4 * 4 + r;
      float tot = rs[lrow] + rs[128 + lrow] + rs[256 + lrow] + rs[384 + lrow];
      float totq = rq[lrow] + rq[128 + lrow] + rq[256 + lrow] + rq[384 + lrow];
      float mean = tot * (1.0f / CC);
      float var = totq * (1.0f / CC) - mean * mean;
      float rstd = rsqrtf(var + 1e-5f);
      int row = m0 + lrow;
#pragma unroll
      for (int ni = 0; ni < 4; ++ni) {
        size_t idx = fb + (size_t)row * 256 + colB + ni * 16;
        float v = vkeep[mi][r][ni];         // from registers, no re-read
        xout[idx] = f2b((v - mean) * rstd * lwv[ni] + lbv[ni]);
      }
    }
  }
}

// ---------- fused MLP (r4-proven, NO LN fusion): fx += gelu(xln@w1+b1)@w2+b2 ----------
__global__ __launch_bounds__(512, 4) void mlp_fused_kernel(
    const bf16* __restrict__ xln, const bf16* __restrict__ w1t,
    const float* __restrict__ b1, const bf16* __restrict__ w2t,
    const float* __restrict__ b2, float* __restrict__ fx) {
  __shared__ __align__(16) unsigned short As[64 * 256];   // 32 KiB (per-64 XOR swizzle)
  __shared__ __align__(16) bf16 Hs[64 * 128];             // 16 KiB
  __shared__ __align__(16) unsigned short Wb[256 * 64];   // 32 KiB weight staging
  int m0 = blockIdx.x * 64;
  int t = threadIdx.x, lane = t & 63, wid = t >> 6;       // wid 0..7
  int l15 = lane & 15, q4 = lane >> 4;
  int wm2 = (wid & 1) * 32, wn2 = (wid >> 1) * 32;
  int wm = (wid & 1) * 32, wn = (wid >> 1) * 64;

  const unsigned short* xg = (const unsigned short*)xln + (size_t)m0 * 256;
#pragma unroll
  for (int i = 0; i < 4; ++i) {
    int u = t + i * 512;
    int row = u >> 5, v = u & 31;
    int kb = v >> 3, jp = v & 7;
    uint4 val = ((const uint4*)xg)[u];
    ((uint4*)As)[row * 32 + kb * 8 + (jp ^ (row & 7))] = val;
  }

  f32x4 accO[2][4];
#pragma unroll
  for (int mi = 0; mi < 2; ++mi)
#pragma unroll
    for (int ni = 0; ni < 4; ++ni) accO[mi][ni] = (f32x4){0.f, 0.f, 0.f, 0.f};

  for (int j = 0; j < 8; ++j) {
    int hbase = j * 128;
    f32x4 acc2[2][2];
#pragma unroll
    for (int mi = 0; mi < 2; ++mi)
#pragma unroll
      for (int nj = 0; nj < 2; ++nj) acc2[mi][nj] = (f32x4){0.f, 0.f, 0.f, 0.f};
    for (int kb = 0; kb < 4; ++kb) {
      __syncthreads();
#pragma unroll
      for (int i = 0; i < 2; ++i) {
        int u = t + i * 512;
        int n = u >> 3, jp = u & 7;
        uint4 val = *(const uint4*)(w1t + (size_t)(hbase + n) * 256 + kb * 64 + jp * 8);
        ((uint4*)Wb)[n * 8 + (jp ^ (n & 7))] = val;
      }
      __syncthreads();
#pragma unroll
      for (int ks = 0; ks < 2; ++ks) {
        int kgrp = ks * 4 + q4;
        bfv8 af[2], bfr[2];
#pragma unroll
        for (int mi = 0; mi < 2; ++mi) {
          int row = wm2 + mi * 16 + l15;
          af[mi] = *(const bfv8*)(&As[row * 256 + kb * 64 + ((kgrp ^ (row & 7)) << 3)]);
        }
#pragma unroll
        for (int nj = 0; nj < 2; ++nj) {
          int n = wn2 + nj * 16 + l15;
          bfr[nj] = *(const bfv8*)(&Wb[n * 64 + ((kgrp ^ (n & 7)) << 3)]);
        }
#pragma unroll
        for (int mi = 0; mi < 2; ++mi)
#pragma unroll
          for (int nj = 0; nj < 2; ++nj)
            acc2[mi][nj] = __builtin_amdgcn_mfma_f32_16x16x32_bf16(af[mi], bfr[nj], acc2[mi][nj], 0, 0, 0);
      }
    }
#pragma unroll
    for (int nj = 0; nj < 2; ++nj) {
      int coln = wn2 + nj * 16 + l15;
      float bv = b1[hbase + coln];
      int half = coln >> 6, sub = (coln >> 3) & 7, lo = coln & 7;
#pragma unroll
      for (int mi = 0; mi < 2; ++mi) {
#pragma unroll
        for (int r = 0; r < 4; ++r) {
          int row = wm2 + mi * 16 + q4 * 4 + r;
          float v = acc2[mi][nj][r] + bv;
          Hs[row * 128 + half * 64 + (((sub ^ (row & 7)) << 3) + lo)] = f2b(gelu_exact(v));
        }
      }
    }
    for (int kb2 = 0; kb2 < 2; ++kb2) {
      __syncthreads();
#pragma unroll
      for (int i = 0; i < 4; ++i) {
        int u = t + i * 512;
        int n = u >> 3, jp = u & 7;
        uint4 val = *(const uint4*)(w2t + (size_t)n * 1024 + hbase + kb2 * 64 + jp * 8);
        ((uint4*)Wb)[n * 8 + (jp ^ (n & 7))] = val;
      }
      __syncthreads();
#pragma unroll
      for (int ks = 0; ks < 2; ++ks) {
        int kgrp = ks * 4 + q4;
        bfv8 af[2], bfr[4];
#pragma unroll
        for (int mi = 0; mi < 2; ++mi) {
          int row = wm + mi * 16 + l15;
          af[mi] = *(const bfv8*)(&Hs[row * 128 + kb2 * 64 + ((kgrp ^ (row & 7)) << 3)]);
        }
#pragma unroll
        for (int ni = 0; ni < 4; ++ni) {
          int n = wn + ni * 16 + l15;
          bfr[ni] = *(const bfv8*)(&Wb[n * 64 + ((kgrp ^ (n & 7)) << 3)]);
        }
#pragma unroll
        for (int mi = 0; mi < 2; ++mi)
#pragma unroll
          for (int ni = 0; ni < 4; ++ni)
            accO[mi][ni] = __builtin_amdgcn_mfma_f32_16x16x32_bf16(af[mi], bfr[ni], accO[mi][ni], 0, 0, 0);
      }
    }
  }
  // ---- epilogue: fx += accO + b2 ----
#pragma unroll
  for (int ni = 0; ni < 4; ++ni) {
    int col = wn + ni * 16 + l15;
    float bv = b2[col];
#pragma unroll
    for (int mi = 0; mi < 2; ++mi) {
#pragma unroll
      for (int r = 0; r < 4; ++r) {
        int row = m0 + wm + mi * 16 + q4 * 4 + r;
        fx[(size_t)row * 256 + col] += accO[mi][ni][r] + bv;
      }
    }
  }
}

// ---------- slice logits + softmax: slice weights in REGISTERS (lane g) ----------
__global__ __launch_bounds__(256) void slice_softmax_kernel(
    const bf16* __restrict__ xmid, const float* __restrict__ sw_w,
    const float* __restrict__ sw_b, const float* __restrict__ temp,
    bf16* __restrict__ swout) {
  __shared__ float xm[SSP][256];    // 16 KiB
  int p0 = blockIdx.x * SSP;
  int t = threadIdx.x;
  int g = t & 63, pq = t >> 6;
  float wreg[32];
#pragma unroll
  for (int d = 0; d < 32; ++d) wreg[d] = sw_w[d * 64 + g];   // coalesced per d
  float bg = sw_b[g];
  float rt[8];
#pragma unroll
  for (int h = 0; h < 8; ++h) rt[h] = 1.0f / fminf(fmaxf(temp[h], 0.1f), 5.0f);
  const unsigned short* xg = (const unsigned short*)xmid + (size_t)p0 * 256;
#pragma unroll
  for (int i2 = t; i2 < SSP * 32; i2 += 256) {
    uint4 v = ((const uint4*)xg)[i2];
    int p = i2 >> 5, c = (i2 & 31) << 3;
    xm[p][c + 0] = us2f((unsigned short)(v.x & 0xffff));
    xm[p][c + 1] = us2f((unsigned short)(v.x >> 16));
    xm[p][c + 2] = us2f((unsigned short)(v.y & 0xffff));
    xm[p][c + 3] = us2f((unsigned short)(v.y >> 16));
    xm[p][c + 4] = us2f((unsigned short)(v.z & 0xffff));
    xm[p][c + 5] = us2f((unsigned short)(v.z >> 16));
    xm[p][c + 6] = us2f((unsigned short)(v.w & 0xffff));
    xm[p][c + 7] = us2f((unsigned short)(v.w >> 16));
  }
  __syncthreads();
  for (int pp2 = 0; pp2 < SSP / 4; ++pp2) {
    int p = pp2 * 4 + pq;
#pragma unroll
    for (int h = 0; h < NHEADS; ++h) {
      float acc = bg;
      const float* xr = &xm[p][h * 32];
#pragma unroll
      for (int d = 0; d < 32; ++d) acc += xr[d] * wreg[d];
      float logit = acc * rt[h];
      float m = logit;
#pragma unroll
      for (int off = 32; off > 0; off >>= 1) m = fmaxf(m, __shfl_xor(m, off, 64));
      float e = __expf(logit - m);
      float s = e;
#pragma unroll
      for (int off = 32; off > 0; off >>= 1) s += __shfl_xor(s, off, 64);
      swout[(size_t)(p0 + p) * 512 + h * 64 + g] = f2b(e / s);
    }
  }
}

// ---------- slice reduce as split-K MFMA outer product (unchanged) ----------
__global__ __launch_bounds__(256) void slice_st_kernel(
    const bf16* __restrict__ fxmid, const bf16* __restrict__ sw,
    float* __restrict__ stp, float* __restrict__ normp) {
  __shared__ __align__(16) unsigned short sw_s[64 * 64];
  __shared__ __align__(16) unsigned short fx_s[32 * 64];
  __shared__ float npart[2][64];
  int split = blockIdx.x, h = blockIdx.y, b = blockIdx.z;
  int t = threadIdx.x, w = t >> 6, lane = t & 63;
  int l15 = lane & 15, q4 = lane >> 4;
  int ns0 = split * (NN / SPLIT);
  const int NT = (NN / SPLIT) / 64;
  f32x4 acc0 = {0.f, 0.f, 0.f, 0.f}, acc1 = {0.f, 0.f, 0.f, 0.f};
  float nacc = 0.f;
  const unsigned short* swg = (const unsigned short*)sw + (size_t)b * NN * 512 + h * 64;
  const unsigned short* fxg = (const unsigned short*)fxmid + (size_t)b * NN * 256 + h * 32;

  for (int kt = 0; kt < NT; ++kt) {
    int n0 = ns0 + kt * 64;
    __syncthreads();
    if (w < 2) {
      int g = lane;
#pragma unroll
      for (int i = 0; i < 4; ++i) {
        int j = w + 2 * i;
        const unsigned short* p = swg + (size_t)(n0 + j * 8) * 512 + g;
        unsigned short v0 = p[0],     v1 = p[512],  v2 = p[1024], v3 = p[1536];
        unsigned short v4 = p[2048],  v5 = p[2560], v6 = p[3072], v7 = p[3584];
        nacc += us2f(v0) + us2f(v1) + us2f(v2) + us2f(v3) +
                us2f(v4) + us2f(v5) + us2f(v6) + us2f(v7);
        uint4 pk = make_uint4((unsigned)v0 | ((unsigned)v1 << 16),
                              (unsigned)v2 | ((unsigned)v3 << 16),
                              (unsigned)v4 | ((unsigned)v5 << 16),
                              (unsigned)v6 | ((unsigned)v7 << 16));
        ((uint4*)sw_s)[g * 8 + (j ^ (g & 7))] = pk;
      }
    } else {
      int d = lane & 31, nh = lane >> 5, w3 = w - 2;
#pragma unroll
      for (int i = 0; i < 2; ++i) {
        int nbase = (w3 * 2 + i) * 16 + nh * 8;
        const unsigned short* p = fxg + (size_t)(n0 + nbase) * 256 + d;
        unsigned short v0 = p[0],    v1 = p[256],  v2 = p[512],  v3 = p[768];
        unsigned short v4 = p[1024], v5 = p[1280], v6 = p[1536], v7 = p[1792];
        uint4 pk = make_uint4((unsigned)v0 | ((unsigned)v1 << 16),
                              (unsigned)v2 | ((unsigned)v3 << 16),
                              (unsigned)v4 | ((unsigned)v5 << 16),
                              (unsigned)v6 | ((unsigned)v7 << 16));
        int u = nbase >> 3;
        ((uint4*)fx_s)[d * 8 + (u ^ (d & 7))] = pk;
      }
    }
    __syncthreads();
    int gg = w * 16 + l15;
    int d0 = l15, d1 = 16 + l15;
#pragma unroll
    for (int ks = 0; ks < 2; ++ks) {
      bfv8 af  = ((const bfv8*)sw_s)[gg * 8 + ((ks * 4 + q4) ^ (gg & 7))];
      bfv8 bf0 = ((const bfv8*)fx_s)[d0 * 8 + ((ks * 4 + q4) ^ (d0 & 7))];
      bfv8 bf1 = ((const bfv8*)fx_s)[d1 * 8 + ((ks * 4 + q4) ^ (d1 & 7))];
      acc0 = __builtin_amdgcn_mfma_f32_16x16x32_bf16(af, bf0, acc0, 0, 0, 0);
      acc1 = __builtin_amdgcn_mfma_f32_16x16x32_bf16(af, bf1, acc1, 0, 0, 0);
    }
  }
  if (w < 2) npart[w][lane] = nacc;
  __syncthreads();
  int bh = b * NHEADS + h;
  if (t < 64) normp[(size_t)split * (BB * NHEADS * GG) + bh * 64 + t] = npart[0][t] + npart[1][t];
  size_t base = ((size_t)split * (BB * NHEADS * GG) + bh * 64) * 32;
#pragma unroll
  for (int r = 0; r < 4; ++r) {
    int g = w * 16 + q4 * 4 + r;
    stp[base + (size_t)g * 32 + l15] = acc0[r];
    stp[base + (size_t)g * 32 + 16 + l15] = acc1[r];
  }
}

// ---------- fused attention + wo-column projection per (b,h) ----------
__global__ __launch_bounds__(256) void attn_wc_kernel(
    const float* __restrict__ stp, const float* __restrict__ normp,
    const float* __restrict__ wq, const float* __restrict__ wk,
    const float* __restrict__ wv, const float* __restrict__ wo,
    bf16* __restrict__ wct) {
  __shared__ float wqs[32 * 32], wks[32 * 32], wvs[32 * 32];
  __shared__ float st[GG][DHD + 1];
  __shared__ float qq[GG][DHD + 1], kk[GG][DHD + 1], vv[GG][DHD + 1];
  __shared__ float pm[GG][GG + 1];
  __shared__ float nrm[GG];
  int bh = blockIdx.x;
  int h2 = bh & 7, bq = bh >> 3;
  int t = threadIdx.x;
  ((float4*)wqs)[t] = ((const float4*)wq)[t];
  ((float4*)wks)[t] = ((const float4*)wk)[t];
  ((float4*)wvs)[t] = ((const float4*)wv)[t];
  float wol[DHD];                           // wo column c = t, loaded early
#pragma unroll
  for (int d = 0; d < DHD; ++d) wol[d] = wo[(size_t)(h2 * DHD + d) * CC + t];
  if (t < 64) {
    float ns = 0.f;
    for (int s = 0; s < SPLIT; ++s) ns += normp[(size_t)s * (BB * NHEADS * GG) + bh * 64 + t];
    nrm[t] = 1.0f / (ns + 1e-5f);
  }
  __syncthreads();
#pragma unroll
  for (int i = 0; i < 8; ++i) {
    int idx = t + i * 256;
    int g = idx >> 5, d = idx & 31;
    float a = 0.f;
    for (int s = 0; s < SPLIT; ++s)
      a += stp[((size_t)s * (BB * NHEADS * GG) + bh * 64 + g) * 32 + d];
    st[g][d] = a * nrm[g];
  }
  __syncthreads();
#pragma unroll
  for (int i = 0; i < 8; ++i) {
    int idx = t + i * 256;
    int g = idx >> 5, d = idx & 31;
    float aq = 0.f, ak = 0.f, av = 0.f;
#pragma unroll
    for (int c = 0; c < 32; ++c) {
      float sv = st[g][c];
      aq += sv * wqs[c * 32 + d];
      ak += sv * wks[c * 32 + d];
      av += sv * wvs[c * 32 + d];
    }
    qq[g][d] = aq; kk[g][d] = ak; vv[g][d] = av;
  }
  __syncthreads();
  {
    int g = t >> 2, sub = t & 3;
    float sc[16];
    float m = -1e30f;
    const float scale = 0.17677669529663687f;
#pragma unroll
    for (int jj = 0; jj < 16; ++jj) {
      int j = sub * 16 + jj;
      float a = 0.f;
#pragma unroll
      for (int d = 0; d < 32; ++d) a += qq[g][d] * kk[j][d];
      a *= scale;
      sc[jj] = a;
      m = fmaxf(m, a);
    }
    m = fmaxf(m, __shfl_xor(m, 1, 64));
    m = fmaxf(m, __shfl_xor(m, 2, 64));
    float ssum = 0.f;
#pragma unroll
    for (int jj = 0; jj < 16; ++jj) { sc[jj] = __expf(sc[jj] - m); ssum += sc[jj]; }
    ssum += __shfl_xor(ssum, 1, 64);
    ssum += __shfl_xor(ssum, 2, 64);
    float rs = 1.0f / ssum;
#pragma unroll
    for (int jj = 0; jj < 16; ++jj) pm[g][sub * 16 + jj] = sc[jj] * rs;
  }
  __syncthreads();
#pragma unroll
  for (int i = 0; i < 8; ++i) {            // PV -> qq (Q dead after scores)
    int idx = t + i * 256;
    int g = idx >> 5, d = idx & 31;
    float a = 0.f;
#pragma unroll
    for (int j = 0; j < GG; ++j) a += pm[g][j] * vv[j][d];
    qq[g][d] = a;
  }
  __syncthreads();
  // wc: wct[b][c][h*64+g] = sum_d ot[g][d] * wo[h*32+d][c], c = t
  bf16* dst = wct + ((size_t)bq * CC + t) * (NHEADS * GG) + h2 * GG;
#pragma unroll 4
  for (int g = 0; g < GG; ++g) {
    float a = 0.f;
#pragma unroll
    for (int d = 0; d < DHD; ++d) a += wol[d] * qq[g][d];
    dst[g] = f2b(a);
  }
}

// ---------- final LN3 + head: one wave per point, float4, no LDS/barrier ----------
__global__ __launch_bounds__(256) void head_kernel(const float* __restrict__ fx,
                                                   const float* __restrict__ w,
                                                   const float* __restrict__ b,
                                                   const float* __restrict__ wout,
                                                   const float* __restrict__ bout,
                                                   float* __restrict__ out) {
  int wid = threadIdx.x >> 6, lane = threadIdx.x & 63;
  int p = blockIdx.x * 4 + wid;
  float4 v = ((const float4*)(fx + (size_t)p * CC))[lane];
  float s = v.x + v.y + v.z + v.w;
  float sq = v.x * v.x + v.y * v.y + v.z * v.z + v.w * v.w;
#pragma unroll
  for (int off = 32; off > 0; off >>= 1) {
    s += __shfl_xor(s, off, 64);
    sq += __shfl_xor(sq, off, 64);
  }
  float mean = s * (1.0f / CC);
  float var = sq * (1.0f / CC) - mean * mean;
  float rstd = rsqrtf(var + 1e-5f);
  float4 wv = ((const float4*)w)[lane];
  float4 bv = ((const float4*)b)[lane];
  float xn0 = (v.x - mean) * rstd * wv.x + bv.x;
  float xn1 = (v.y - mean) * rstd * wv.y + bv.y;
  float xn2 = (v.z - mean) * rstd * wv.z + bv.z;
  float xn3 = (v.w - mean) * rstd * wv.w + bv.w;
  float4 w0 = ((const float4*)wout)[lane * 4 + 0];
  float4 w1 = ((const float4*)wout)[lane * 4 + 1];
  float4 w2 = ((const float4*)wout)[lane * 4 + 2];
  float4 w3 = ((const float4*)wout)[lane * 4 + 3];
  float4 o;
  o.x = xn0 * w0.x + xn1 * w1.x + xn2 * w2.x + xn3 * w3.x;
  o.y = xn0 * w0.y + xn1 * w1.y + xn2 * w2.y + xn3 * w3.y;
  o.z = xn0 * w0.z + xn1 * w1.z + xn2 * w2.z + xn3 * w3.z;
  o.w = xn0 * w0.w + xn1 * w1.w + xn2 * w2.w + xn3 * w3.w;
#pragma unroll
  for (int off = 32; off > 0; off >>= 1) {
    o.x += __shfl_xor(o.x, off, 64);
    o.y += __shfl_xor(o.y, off, 64);
    o.z += __shfl_xor(o.z, off, 64);
    o.w += __shfl_xor(o.w, off, 64);
  }
  if (lane == 0) {
    float4 bo4 = *((const float4*)bout);
    float4 r;
    r.x = o.x + bo4.x; r.y = o.y + bo4.y; r.z = o.z + bo4.z; r.w = o.w + bo4.w;
    ((float4*)out)[p] = r;
  }
}

extern "C" void kernel_launch(void* const* d_in, const int* in_sizes, int n_in,
                              void* d_out, int out_size, void* d_ws, size_t ws_size,
                              hipStream_t stream) {
  const float* fx_in      = (const float*)d_in[0];
  const float* ln1_w      = (const float*)d_in[1];
  const float* ln1_b      = (const float*)d_in[2];
  const float* convx_w    = (const float*)d_in[3];
  const float* convx_b    = (const float*)d_in[4];
  const float* convfx_w   = (const float*)d_in[5];
  const float* convfx_b   = (const float*)d_in[6];
  const float* slice_w    = (const float*)d_in[7];
  const float* slice_b    = (const float*)d_in[8];
  const float* temperature= (const float*)d_in[9];
  const float* wq         = (const float*)d_in[10];
  const float* wk         = (const float*)d_in[11];
  const float* wv         = (const float*)d_in[12];
  const float* wo         = (const float*)d_in[13];
  const float* bo         = (const float*)d_in[14];
  const float* ln2_w      = (const float*)d_in[15];
  const float* ln2_b      = (const float*)d_in[16];
  const float* w1         = (const float*)d_in[17];
  const float* b1         = (const float*)d_in[18];
  const float* w2         = (const float*)d_in[19];
  const float* b2         = (const float*)d_in[20];
  const float* ln3_w      = (const float*)d_in[21];
  const float* ln3_b      = (const float*)d_in[22];
  const float* w_out      = (const float*)d_in[23];
  const float* b_out      = (const float*)d_in[24];
  float* out = (float*)d_out;

  char* ws = (char*)d_ws;
  size_t off = 0;
  auto alloc = [&](size_t bytes) -> void* {
    void* p = ws + off;
    off += (bytes + 255) & ~(size_t)255;
    return p;
  };
  float* fx32  = (float*)alloc((size_t)BB * NN * CC * 4);    // 64 MiB
  bf16* xln    = (bf16*)alloc((size_t)BB * NN * CC * 2);     // 32 MiB
  char* uni    = (char*)alloc((size_t)BB * NN * 512 * 2 * 2);// xmid/fxmid/swb region
  bf16* xmid   = (bf16*)uni;
  bf16* fxmid  = (bf16*)(uni + (size_t)BB * NN * INNERC * 2);
  bf16* swb    = (bf16*)(uni + (size_t)2 * BB * NN * INNERC * 2);
  float* stp   = (float*)uni;                                // 8 MiB (aliases dead xmid)
  float* normp = (float*)(uni + (size_t)SPLIT * BB * NHEADS * GG * DHD * 4);
  bf16* wtx    = (bf16*)alloc((size_t)LL * 9 * CC * INNERC * 2);
  bf16* wtfx   = (bf16*)alloc((size_t)LL * 9 * CC * INNERC * 2);
  bf16* w1t    = (bf16*)alloc((size_t)LL * CC * HIDD * 2);
  bf16* w2t    = (bf16*)alloc((size_t)LL * HIDD * CC * 2);
  bf16* wct    = (bf16*)alloc((size_t)BB * CC * NHEADS * GG * 2);   // 1 MiB
  float* zbuf  = (float*)alloc(256);                          // zero pad for conv halo
  (void)ws_size; (void)in_sizes; (void)n_in; (void)out_size;

  hipMemsetAsync(zbuf, 0, 256, stream);

  transpose_cast_kernel<<<dim3(8, 8, LL * 9), 256, 0, stream>>>(convx_w, wtx, CC, INNERC);
  transpose_cast_kernel<<<dim3(8, 8, LL * 9), 256, 0, stream>>>(convfx_w, wtfx, CC, INNERC);
  transpose_cast_kernel<<<dim3(32, 8, LL), 256, 0, stream>>>(w1, w1t, CC, HIDD);
  transpose_cast_kernel<<<dim3(8, 32, LL), 256, 0, stream>>>(w2, w2t, HIDD, CC);

  hipMemcpyAsync(fx32, fx_in, (size_t)BB * NN * CC * sizeof(float),
                 hipMemcpyDeviceToDevice, stream);

  const int M = BB * NN;  // 65536
  ln_kernel<<<M / 4, 256, 0, stream>>>(fx32, ln1_w, ln1_b, xln);
  for (int i = 0; i < LL; ++i) {
    conv_mfma_kernel<<<BB * HH / 2, 512, 0, stream>>>(
        xln, wtfx + (size_t)i * 9 * CC * INNERC, convfx_b + i * INNERC, fxmid,
        (const float*)zbuf);
    conv_mfma_kernel<<<BB * HH / 2, 512, 0, stream>>>(
        xln, wtx + (size_t)i * 9 * CC * INNERC, convx_b + i * INNERC, xmid,
        (const float*)zbuf);
    slice_softmax_kernel<<<M / SSP, 256, 0, stream>>>(
        xmid, slice_w + i * DHD * GG, slice_b + i * GG, temperature + i * NHEADS, swb);
    slice_st_kernel<<<dim3(SPLIT, NHEADS, BB), 256, 0, stream>>>(fxmid, swb, stp, normp);
    attn_wc_kernel<<<BB * NHEADS, 256, 0, stream>>>(
        stp, normp, wq + i * DHD * DHD, wk + i * DHD * DHD, wv + i * DHD * DHD,
        wo + (size_t)i * INNERC * CC, wct);
    // fx += sw @ Wc + bo, then xln = ln2(fx)  (deslice + wo-proj + residual + LN fused)
    gemm_ln_kernel<<<dim3(NN / 128, BB), 512, 0, stream>>>(
        swb, wct, bo + i * CC, fx32, ln2_w + i * CC, ln2_b + i * CC, xln);
    // fx += mlp(xln)  (r4-proven, no LN fusion)
    mlp_fused_kernel<<<M / 64, 512, 0, stream>>>(
        xln, w1t + (size_t)i * CC * HIDD, b1 + i * HIDD,
        w2t + (size_t)i * HIDD * CC, b2 + i * CC, fx32);
    if (i < LL - 1)
      ln_kernel<<<M / 4, 256, 0, stream>>>(fx32, ln1_w + (i + 1) * CC,
                                           ln1_b + (i + 1) * CC, xln);
  }
  head_kernel<<<M / 4, 256, 0, stream>>>(fx32, ln3_w, ln3_b, w_out, b_out, out);
}

// Round 11
// 2214.590 us; speedup vs baseline: 1.0810x; 1.0167x over previous
//
#include <hip/hip_runtime.h>
#include <hip/hip_bf16.h>

typedef __hip_bfloat16 bf16;
typedef __bf16 bfv8 __attribute__((ext_vector_type(8)));
typedef float f32x4 __attribute__((ext_vector_type(4)));

#define BB 4
#define HH 128
#define WWI 128
#define NN 16384      // HH*WWI
#define CC 256
#define LL 4
#define NHEADS 8
#define DHD 32
#define GG 64
#define INNERC 256    // NHEADS*DHD
#define HIDD 1024
#define SPLIT 32      // split-K blocks per (b,h) in slice_st
#define SSP 16        // points per block in slice_softmax

__device__ __forceinline__ float b2f(bf16 x) { return __bfloat162float(x); }
__device__ __forceinline__ bf16 f2b(float x) { return __float2bfloat16(x); }
__device__ __forceinline__ float us2f(unsigned short v) {
  return __uint_as_float(((unsigned)v) << 16);
}
__device__ __forceinline__ unsigned short b2us(bf16 h) {
  union { bf16 b; unsigned short u; } c; c.b = h; return c.u;
}

// async global->LDS, 16B per lane; LDS dest = wave-uniform base + lane*16
__device__ __forceinline__ void async16(void* l, const void* g) {
  __builtin_amdgcn_global_load_lds(
      (const __attribute__((address_space(1))) void*)g,
      (__attribute__((address_space(3))) void*)l, 16, 0, 0);
}

__device__ __forceinline__ float wave_sum(float v) {
#pragma unroll
  for (int off = 32; off > 0; off >>= 1) v += __shfl_down(v, off, 64);
  return v;
}

__device__ __forceinline__ float gelu_exact(float x) {
  return 0.5f * x * (1.0f + erff(x * 0.70710678118654752f));
}

// ---------- batched transpose+cast: src fp32 [T][R][Cm] -> dst bf16 [T][Cm][R] ----------
__global__ void transpose_cast_kernel(const float* __restrict__ src, bf16* __restrict__ dst,
                                      int R, int Cm) {
  __shared__ float tile[32][33];
  int tb = blockIdx.z;
  const float* s = src + (size_t)tb * R * Cm;
  bf16* d = dst + (size_t)tb * R * Cm;
  int c0 = blockIdx.x * 32, r0 = blockIdx.y * 32;
  int tx = threadIdx.x & 31, ty = threadIdx.x >> 5;  // 32 x 8
  for (int rr = ty; rr < 32; rr += 8) {
    int r = r0 + rr, c = c0 + tx;
    tile[rr][tx] = (r < R && c < Cm) ? s[(size_t)r * Cm + c] : 0.f;
  }
  __syncthreads();
  for (int cc = ty; cc < 32; cc += 8) {
    int c = c0 + cc, r = r0 + tx;
    if (c < Cm && r < R) d[(size_t)c * R + r] = f2b(tile[tx][cc]);
  }
}

// ---------- LayerNorm (ln1): one wave per point, float4 loads, no LDS/barrier ----------
__global__ __launch_bounds__(256) void ln_kernel(const float* __restrict__ x,
                                                 const float* __restrict__ w,
                                                 const float* __restrict__ b,
                                                 bf16* __restrict__ out) {
  int wid = threadIdx.x >> 6, lane = threadIdx.x & 63;
  int p = blockIdx.x * 4 + wid;
  float4 v = ((const float4*)(x + (size_t)p * CC))[lane];
  float s = v.x + v.y + v.z + v.w;
  float sq = v.x * v.x + v.y * v.y + v.z * v.z + v.w * v.w;
#pragma unroll
  for (int off = 32; off > 0; off >>= 1) {
    s += __shfl_xor(s, off, 64);
    sq += __shfl_xor(sq, off, 64);
  }
  float mean = s * (1.0f / CC);
  float var = sq * (1.0f / CC) - mean * mean;
  float rstd = rsqrtf(var + 1e-5f);
  float4 wv = ((const float4*)w)[lane];
  float4 bv = ((const float4*)b)[lane];
  unsigned short o0 = b2us(f2b((v.x - mean) * rstd * wv.x + bv.x));
  unsigned short o1 = b2us(f2b((v.y - mean) * rstd * wv.y + bv.y));
  unsigned short o2 = b2us(f2b((v.z - mean) * rstd * wv.z + bv.z));
  unsigned short o3 = b2us(f2b((v.w - mean) * rstd * wv.w + bv.w));
  uint2 pk = make_uint2((unsigned)o0 | ((unsigned)o1 << 16),
                        (unsigned)o2 | ((unsigned)o3 << 16));
  ((uint2*)(out + (size_t)p * CC))[lane] = pk;
}

// ---------- 3x3 conv as implicit MFMA GEMM, v3 (unchanged) ----------
__global__ __launch_bounds__(512, 2) void conv_mfma_kernel(
    const bf16* __restrict__ xln, const bf16* __restrict__ wt,
    const float* __restrict__ bias, bf16* __restrict__ out,
    const float* __restrict__ zbuf) {
  __shared__ __align__(16) unsigned short As[4 * 130 * 64];   // 65 KiB (rows h0-1..h0+2)
  __shared__ __align__(16) unsigned short Bsm[2][256 * 64];   // 2 x 32 KiB
  int bid = blockIdx.x;
  bid = (bid & 7) * 32 + (bid >> 3);        // XCD swizzle (256 = 8*32, bijective)
  int h0 = (bid & 63) * 2;                  // output row pair
  int b = bid >> 6;
  int t = threadIdx.x, lane = t & 63, wid = t >> 6;
  int r = wid & 1;                          // output row within pair
  int wn = (wid >> 1) * 64;                 // oc quarter
  int l15 = lane & 15, l4 = lane >> 4;
  int wu = t & ~63;                         // wave-uniform thread base
  f32x4 acc[8][4];
#pragma unroll
  for (int mi = 0; mi < 8; ++mi)
#pragma unroll
    for (int ni = 0; ni < 4; ++ni) acc[mi][ni] = (f32x4){0.f, 0.f, 0.f, 0.f};
  const bf16* xbase = xln + (size_t)b * NN * CC;

  auto stageB = [&](int buf, int tap, int q) {
#pragma unroll
    for (int k = 0; k < 4; ++k) {
      int u = t + k * 512;
      int n = u >> 3, jp = u & 7, j = jp ^ (n & 7);
      async16(&Bsm[buf][(size_t)(wu + k * 512) * 8],
              wt + ((size_t)(tap * 256 + n)) * 256 + q * 64 + j * 8);
    }
  };

  for (int q = 0; q < 4; ++q) {             // 64-channel K chunks
#pragma unroll
    for (int k = 0; k < 8; ++k) {
      int u = t + k * 512;
      int jp = u & 7, pc = u >> 3;
      int ar = pc / 130, cl = pc - ar * 130;
      int j = jp ^ (cl & 7);
      int gr = h0 + ar - 1, gc = cl - 1;
      const void* src =
          ((unsigned)gr < 128u && (unsigned)gc < 128u)
              ? (const void*)(xbase + ((size_t)(gr * WWI + gc)) * CC + q * 64 + j * 8)
              : (const void*)zbuf;
      async16(&As[(size_t)(wu + k * 512) * 8], src);
    }
    if (t < 64) {
      int u = t + 4096;
      int jp = u & 7, pc = u >> 3;
      int ar = pc / 130, cl = pc - ar * 130;
      int j = jp ^ (cl & 7);
      int gr = h0 + ar - 1, gc = cl - 1;
      const void* src =
          ((unsigned)gr < 128u && (unsigned)gc < 128u)
              ? (const void*)(xbase + ((size_t)(gr * WWI + gc)) * CC + q * 64 + j * 8)
              : (const void*)zbuf;
      async16(&As[(size_t)4096 * 8], src);
    }
    if (q == 0) stageB(0, 0, 0);
    __syncthreads();

    for (int tap = 0; tap < 9; ++tap) {
      int cur = (q * 9 + tap) & 1;
      if (tap < 8)      stageB(cur ^ 1, tap + 1, q);
      else if (q < 3)   stageB(cur ^ 1, 0, q + 1);
      int ky = tap / 3, kx = tap - ky * 3;
      const unsigned short* Bc = Bsm[cur];
#pragma unroll
      for (int s = 0; s < 2; ++s) {
        bfv8 af[8], bfr[4];
#pragma unroll
        for (int mi = 0; mi < 8; ++mi) {
          int cl = mi * 16 + l15 + kx;
          af[mi] = *(const bfv8*)(&As[((size_t)((ky + r) * 130 + cl)) * 64 +
                                      (((s * 4 + l4) ^ (cl & 7)) << 3)]);
        }
#pragma unroll
        for (int ni = 0; ni < 4; ++ni) {
          int rn = wn + ni * 16 + l15;
          bfr[ni] = *(const bfv8*)(&Bc[(size_t)rn * 64 + (((s * 4 + l4) ^ (rn & 7)) << 3)]);
        }
#pragma unroll
        for (int mi = 0; mi < 8; ++mi)
#pragma unroll
          for (int ni = 0; ni < 4; ++ni)
            acc[mi][ni] = __builtin_amdgcn_mfma_f32_16x16x32_bf16(af[mi], bfr[ni], acc[mi][ni], 0, 0, 0);
      }
      __syncthreads();
    }
  }
  int colB = wn + l15;
  int rowB = l4 * 4;
#pragma unroll
  for (int ni = 0; ni < 4; ++ni) {
    int oc = colB + ni * 16;
    float bv = bias[oc];
#pragma unroll
    for (int mi = 0; mi < 8; ++mi) {
#pragma unroll
      for (int rr = 0; rr < 4; ++rr) {
        int pix = mi * 16 + rowB + rr;
        out[((size_t)(b * NN + (h0 + r) * WWI + pix)) * CC + oc] = f2b(acc[mi][ni][rr] + bv);
      }
    }
  }
}

// ---------- fused deslice GEMM + residual + LN2 (unchanged) ----------
__global__ __launch_bounds__(512) void gemm_ln_kernel(
    const bf16* __restrict__ A, const bf16* __restrict__ BT,
    const float* __restrict__ bias, float* __restrict__ fx,
    const float* __restrict__ lw, const float* __restrict__ lb,
    bf16* __restrict__ xout) {
  __shared__ __align__(16) unsigned short As[128 * 64];   // 16 KiB
  __shared__ __align__(16) unsigned short Bs[256 * 64];   // 32 KiB
  int z = blockIdx.y;
  const bf16* Aa = A + (size_t)z * NN * 512;
  const bf16* Ba = BT + (size_t)z * 256 * 512;
  size_t fb = (size_t)z * NN * 256;
  int m0 = blockIdx.x * 128;
  int t = threadIdx.x, lane = t & 63, wid = t >> 6;
  int wm = (wid & 1) * 64, wn = (wid >> 1) * 64;
  int l15 = lane & 15, q4 = lane >> 4;
  int wu = t & ~63;
  f32x4 acc[4][4];
#pragma unroll
  for (int mi = 0; mi < 4; ++mi)
#pragma unroll
    for (int ni = 0; ni < 4; ++ni) acc[mi][ni] = (f32x4){0.f, 0.f, 0.f, 0.f};

  for (int kb = 0; kb < 512; kb += 64) {
    __syncthreads();
#pragma unroll
    for (int i = 0; i < 2; ++i) {          // A: 128 rows x 64k = 1024 units
      int u = t + i * 512;
      int row = u >> 3, jp = u & 7, j = jp ^ (row & 7);
      async16(&As[(size_t)(wu + i * 512) * 8], Aa + (size_t)(m0 + row) * 512 + kb + j * 8);
    }
#pragma unroll
    for (int i = 0; i < 4; ++i) {          // B: 256 rows x 64k = 2048 units
      int u = t + i * 512;
      int n = u >> 3, jp = u & 7, j = jp ^ (n & 7);
      async16(&Bs[(size_t)(wu + i * 512) * 8], Ba + (size_t)n * 512 + kb + j * 8);
    }
    __syncthreads();
#pragma unroll
    for (int s = 0; s < 2; ++s) {
      int kgrp = s * 4 + q4;
      bfv8 af[4], bfr[4];
#pragma unroll
      for (int mi = 0; mi < 4; ++mi) {
        int row = wm + mi * 16 + l15;
        af[mi] = *(const bfv8*)(&As[(size_t)row * 64 + ((kgrp ^ (row & 7)) << 3)]);
      }
#pragma unroll
      for (int ni = 0; ni < 4; ++ni) {
        int n = wn + ni * 16 + l15;
        bfr[ni] = *(const bfv8*)(&Bs[(size_t)n * 64 + ((kgrp ^ (n & 7)) << 3)]);
      }
#pragma unroll
      for (int mi = 0; mi < 4; ++mi)
#pragma unroll
        for (int ni = 0; ni < 4; ++ni)
          acc[mi][ni] = __builtin_amdgcn_mfma_f32_16x16x32_bf16(af[mi], bfr[ni], acc[mi][ni], 0, 0, 0);
    }
  }
  // ---- epilogue: v = fx + acc + bias; stats; ln2 -> xout ----
  __syncthreads();                          // all waves past As/Bs reads; alias As
  float* rs = (float*)As;                   // [4][128]
  float* rq = rs + 512;                     // [4][128]
  int cw = wid >> 1;
  int colB = wn + l15;
  float bv[4], lwv[4], lbv[4];
#pragma unroll
  for (int ni = 0; ni < 4; ++ni) {
    bv[ni] = bias[colB + ni * 16];
    lwv[ni] = lw[colB + ni * 16];
    lbv[ni] = lb[colB + ni * 16];
  }
  float vkeep[4][4][4];
#pragma unroll
  for (int mi = 0; mi < 4; ++mi) {
#pragma unroll
    for (int r = 0; r < 4; ++r) {
      int row = m0 + wm + mi * 16 + q4 * 4 + r;
      float s = 0.f, sq = 0.f;
#pragma unroll
      for (int ni = 0; ni < 4; ++ni) {
        size_t idx = fb + (size_t)row * 256 + colB + ni * 16;
        float v = fx[idx] + acc[mi][ni][r] + bv[ni];
        fx[idx] = v;
        vkeep[mi][r][ni] = v;
        s += v; sq += v * v;
      }
#pragma unroll
      for (int off = 1; off < 16; off <<= 1) {
        s += __shfl_xor(s, off, 64);
        sq += __shfl_xor(sq, off, 64);
      }
      if (l15 == 0) {
        int lrow = wm + mi * 16 + q4 * 4 + r;
        rs[cw * 128 + lrow] = s;
        rq[cw * 128 + lrow] = sq;
      }
    }
  }
  __syncthreads();
#pragma unroll
  for (int mi = 0; mi < 4; ++mi) {
#pragma unroll
    for (int r = 0; r < 4; ++r) {
      int lrow = wm + mi * 16 + q4 * 4 + r;
      float tot = rs[lrow] + rs[128 + lrow] + rs[256 + lrow] + rs[384 + lrow];
      float totq = rq[lrow] + rq[128 + lrow] + rq[256 + lrow] + rq[384 + lrow];
      float mean = tot * (1.0f / CC);
      float var = totq * (1.0f / CC) - mean * mean;
      float rstd = rsqrtf(var + 1e-5f);
      int row = m0 + lrow;
#pragma unroll
      for (int ni = 0; ni < 4; ++ni) {
        size_t idx = fb + (size_t)row * 256 + colB + ni * 16;
        float v = vkeep[mi][r][ni];         // from registers, no re-read
        xout[idx] = f2b((v - mean) * rstd * lwv[ni] + lbv[ni]);
      }
    }
  }
}

// ---------- fused MLP v5: r4 structure, W/A staging via global_load_lds ----------
// Identical LDS layout / barriers / tiling to the r4-proven kernel; only the staging
// loads changed from register-roundtrip to async16 with the XOR swizzle folded into
// the per-lane GLOBAL source (involution; conv/gemm_ln-proven pattern).
__global__ __launch_bounds__(512, 4) void mlp_fused_kernel(
    const bf16* __restrict__ xln, const bf16* __restrict__ w1t,
    const float* __restrict__ b1, const bf16* __restrict__ w2t,
    const float* __restrict__ b2, float* __restrict__ fx) {
  __shared__ __align__(16) unsigned short As[64 * 256];   // 32 KiB (per-64 XOR swizzle)
  __shared__ __align__(16) bf16 Hs[64 * 128];             // 16 KiB
  __shared__ __align__(16) unsigned short Wb[256 * 64];   // 32 KiB weight staging
  int m0 = blockIdx.x * 64;
  int t = threadIdx.x, lane = t & 63, wid = t >> 6;       // wid 0..7
  int l15 = lane & 15, q4 = lane >> 4;
  int wm2 = (wid & 1) * 32, wn2 = (wid >> 1) * 32;
  int wm = (wid & 1) * 32, wn = (wid >> 1) * 64;
  int wu = t & ~63;

  // stage A (xln rows m0..m0+63, full K=256) — once, async.
  // LDS unit u holds src unit (u&~7)|((u&7)^(row&7)) (XOR involution).
  const unsigned short* xg = (const unsigned short*)xln + (size_t)m0 * 256;
#pragma unroll
  for (int i = 0; i < 4; ++i) {
    int u = t + i * 512;
    int row = u >> 5;
    int su = (u & ~7) | ((u & 7) ^ (row & 7));
    async16(&As[(size_t)(wu + i * 512) * 8], xg + (size_t)su * 8);
  }

  f32x4 accO[2][4];
#pragma unroll
  for (int mi = 0; mi < 2; ++mi)
#pragma unroll
    for (int ni = 0; ni < 4; ++ni) accO[mi][ni] = (f32x4){0.f, 0.f, 0.f, 0.f};

  for (int j = 0; j < 8; ++j) {           // hidden chunks of 128
    int hbase = j * 128;
    f32x4 acc2[2][2];
#pragma unroll
    for (int mi = 0; mi < 2; ++mi)
#pragma unroll
      for (int nj = 0; nj < 2; ++nj) acc2[mi][nj] = (f32x4){0.f, 0.f, 0.f, 0.f};
    // ---- GEMM1: hidden chunk = A(LDS) @ W1[:, hbase:hbase+128] ----
    for (int kb = 0; kb < 4; ++kb) {
      __syncthreads();
#pragma unroll
      for (int i = 0; i < 2; ++i) {       // stage W1T chunk [128 n][64 k] = 16 KiB
        int u = t + i * 512;
        int n = u >> 3, j2 = (u & 7) ^ (n & 7);
        async16(&Wb[(size_t)(wu + i * 512) * 8],
                w1t + (size_t)(hbase + n) * 256 + kb * 64 + j2 * 8);
      }
      __syncthreads();
#pragma unroll
      for (int ks = 0; ks < 2; ++ks) {
        int kgrp = ks * 4 + q4;
        bfv8 af[2], bfr[2];
#pragma unroll
        for (int mi = 0; mi < 2; ++mi) {
          int row = wm2 + mi * 16 + l15;
          af[mi] = *(const bfv8*)(&As[row * 256 + kb * 64 + ((kgrp ^ (row & 7)) << 3)]);
        }
#pragma unroll
        for (int nj = 0; nj < 2; ++nj) {
          int n = wn2 + nj * 16 + l15;
          bfr[nj] = *(const bfv8*)(&Wb[n * 64 + ((kgrp ^ (n & 7)) << 3)]);
        }
#pragma unroll
        for (int mi = 0; mi < 2; ++mi)
#pragma unroll
          for (int nj = 0; nj < 2; ++nj)
            acc2[mi][nj] = __builtin_amdgcn_mfma_f32_16x16x32_bf16(af[mi], bfr[nj], acc2[mi][nj], 0, 0, 0);
      }
    }
    // ---- +b1, gelu, pack to Hs (bf16) ----
#pragma unroll
    for (int nj = 0; nj < 2; ++nj) {
      int coln = wn2 + nj * 16 + l15;
      float bv = b1[hbase + coln];
      int half = coln >> 6, sub = (coln >> 3) & 7, lo = coln & 7;
#pragma unroll
      for (int mi = 0; mi < 2; ++mi) {
#pragma unroll
        for (int r = 0; r < 4; ++r) {
          int row = wm2 + mi * 16 + q4 * 4 + r;
          float v = acc2[mi][nj][r] + bv;
          Hs[row * 128 + half * 64 + (((sub ^ (row & 7)) << 3) + lo)] = f2b(gelu_exact(v));
        }
      }
    }
    // ---- GEMM2: out += H(LDS) @ W2[hbase:hbase+128, :] ----
    for (int kb2 = 0; kb2 < 2; ++kb2) {
      __syncthreads();                    // Hs visible (first iter); Wb free
#pragma unroll
      for (int i = 0; i < 4; ++i) {       // stage W2T chunk [256 n][64 k] = 32 KiB
        int u = t + i * 512;
        int n = u >> 3, j2 = (u & 7) ^ (n & 7);
        async16(&Wb[(size_t)(wu + i * 512) * 8],
                w2t + (size_t)n * 1024 + hbase + kb2 * 64 + j2 * 8);
      }
      __syncthreads();
#pragma unroll
      for (int ks = 0; ks < 2; ++ks) {
        int kgrp = ks * 4 + q4;
        bfv8 af[2], bfr[4];
#pragma unroll
        for (int mi = 0; mi < 2; ++mi) {
          int row = wm + mi * 16 + l15;
          af[mi] = *(const bfv8*)(&Hs[row * 128 + kb2 * 64 + ((kgrp ^ (row & 7)) << 3)]);
        }
#pragma unroll
        for (int ni = 0; ni < 4; ++ni) {
          int n = wn + ni * 16 + l15;
          bfr[ni] = *(const bfv8*)(&Wb[n * 64 + ((kgrp ^ (n & 7)) << 3)]);
        }
#pragma unroll
        for (int mi = 0; mi < 2; ++mi)
#pragma unroll
          for (int ni = 0; ni < 4; ++ni)
            accO[mi][ni] = __builtin_amdgcn_mfma_f32_16x16x32_bf16(af[mi], bfr[ni], accO[mi][ni], 0, 0, 0);
      }
    }
  }
  // ---- epilogue: fx += accO + b2 ----
#pragma unroll
  for (int ni = 0; ni < 4; ++ni) {
    int col = wn + ni * 16 + l15;
    float bv = b2[col];
#pragma unroll
    for (int mi = 0; mi < 2; ++mi) {
#pragma unroll
      for (int r = 0; r < 4; ++r) {
        int row = m0 + wm + mi * 16 + q4 * 4 + r;
        fx[(size_t)row * 256 + col] += accO[mi][ni][r] + bv;
      }
    }
  }
}

// ---------- slice logits + softmax: slice weights in REGISTERS (lane g) ----------
__global__ __launch_bounds__(256) void slice_softmax_kernel(
    const bf16* __restrict__ xmid, const float* __restrict__ sw_w,
    const float* __restrict__ sw_b, const float* __restrict__ temp,
    bf16* __restrict__ swout) {
  __shared__ float xm[SSP][256];    // 16 KiB
  int p0 = blockIdx.x * SSP;
  int t = threadIdx.x;
  int g = t & 63, pq = t >> 6;
  float wreg[32];
#pragma unroll
  for (int d = 0; d < 32; ++d) wreg[d] = sw_w[d * 64 + g];   // coalesced per d
  float bg = sw_b[g];
  float rt[8];
#pragma unroll
  for (int h = 0; h < 8; ++h) rt[h] = 1.0f / fminf(fmaxf(temp[h], 0.1f), 5.0f);
  const unsigned short* xg = (const unsigned short*)xmid + (size_t)p0 * 256;
#pragma unroll
  for (int i2 = t; i2 < SSP * 32; i2 += 256) {
    uint4 v = ((const uint4*)xg)[i2];
    int p = i2 >> 5, c = (i2 & 31) << 3;
    xm[p][c + 0] = us2f((unsigned short)(v.x & 0xffff));
    xm[p][c + 1] = us2f((unsigned short)(v.x >> 16));
    xm[p][c + 2] = us2f((unsigned short)(v.y & 0xffff));
    xm[p][c + 3] = us2f((unsigned short)(v.y >> 16));
    xm[p][c + 4] = us2f((unsigned short)(v.z & 0xffff));
    xm[p][c + 5] = us2f((unsigned short)(v.z >> 16));
    xm[p][c + 6] = us2f((unsigned short)(v.w & 0xffff));
    xm[p][c + 7] = us2f((unsigned short)(v.w >> 16));
  }
  __syncthreads();
  for (int pp2 = 0; pp2 < SSP / 4; ++pp2) {
    int p = pp2 * 4 + pq;
#pragma unroll
    for (int h = 0; h < NHEADS; ++h) {
      float acc = bg;
      const float* xr = &xm[p][h * 32];
#pragma unroll
      for (int d = 0; d < 32; ++d) acc += xr[d] * wreg[d];
      float logit = acc * rt[h];
      float m = logit;
#pragma unroll
      for (int off = 32; off > 0; off >>= 1) m = fmaxf(m, __shfl_xor(m, off, 64));
      float e = __expf(logit - m);
      float s = e;
#pragma unroll
      for (int off = 32; off > 0; off >>= 1) s += __shfl_xor(s, off, 64);
      swout[(size_t)(p0 + p) * 512 + h * 64 + g] = f2b(e / s);
    }
  }
}

// ---------- slice reduce as split-K MFMA outer product (unchanged) ----------
__global__ __launch_bounds__(256) void slice_st_kernel(
    const bf16* __restrict__ fxmid, const bf16* __restrict__ sw,
    float* __restrict__ stp, float* __restrict__ normp) {
  __shared__ __align__(16) unsigned short sw_s[64 * 64];
  __shared__ __align__(16) unsigned short fx_s[32 * 64];
  __shared__ float npart[2][64];
  int split = blockIdx.x, h = blockIdx.y, b = blockIdx.z;
  int t = threadIdx.x, w = t >> 6, lane = t & 63;
  int l15 = lane & 15, q4 = lane >> 4;
  int ns0 = split * (NN / SPLIT);
  const int NT = (NN / SPLIT) / 64;
  f32x4 acc0 = {0.f, 0.f, 0.f, 0.f}, acc1 = {0.f, 0.f, 0.f, 0.f};
  float nacc = 0.f;
  const unsigned short* swg = (const unsigned short*)sw + (size_t)b * NN * 512 + h * 64;
  const unsigned short* fxg = (const unsigned short*)fxmid + (size_t)b * NN * 256 + h * 32;

  for (int kt = 0; kt < NT; ++kt) {
    int n0 = ns0 + kt * 64;
    __syncthreads();
    if (w < 2) {
      int g = lane;
#pragma unroll
      for (int i = 0; i < 4; ++i) {
        int j = w + 2 * i;
        const unsigned short* p = swg + (size_t)(n0 + j * 8) * 512 + g;
        unsigned short v0 = p[0],     v1 = p[512],  v2 = p[1024], v3 = p[1536];
        unsigned short v4 = p[2048],  v5 = p[2560], v6 = p[3072], v7 = p[3584];
        nacc += us2f(v0) + us2f(v1) + us2f(v2) + us2f(v3) +
                us2f(v4) + us2f(v5) + us2f(v6) + us2f(v7);
        uint4 pk = make_uint4((unsigned)v0 | ((unsigned)v1 << 16),
                              (unsigned)v2 | ((unsigned)v3 << 16),
                              (unsigned)v4 | ((unsigned)v5 << 16),
                              (unsigned)v6 | ((unsigned)v7 << 16));
        ((uint4*)sw_s)[g * 8 + (j ^ (g & 7))] = pk;
      }
    } else {
      int d = lane & 31, nh = lane >> 5, w3 = w - 2;
#pragma unroll
      for (int i = 0; i < 2; ++i) {
        int nbase = (w3 * 2 + i) * 16 + nh * 8;
        const unsigned short* p = fxg + (size_t)(n0 + nbase) * 256 + d;
        unsigned short v0 = p[0],    v1 = p[256],  v2 = p[512],  v3 = p[768];
        unsigned short v4 = p[1024], v5 = p[1280], v6 = p[1536], v7 = p[1792];
        uint4 pk = make_uint4((unsigned)v0 | ((unsigned)v1 << 16),
                              (unsigned)v2 | ((unsigned)v3 << 16),
                              (unsigned)v4 | ((unsigned)v5 << 16),
                              (unsigned)v6 | ((unsigned)v7 << 16));
        int u = nbase >> 3;
        ((uint4*)fx_s)[d * 8 + (u ^ (d & 7))] = pk;
      }
    }
    __syncthreads();
    int gg = w * 16 + l15;
    int d0 = l15, d1 = 16 + l15;
#pragma unroll
    for (int ks = 0; ks < 2; ++ks) {
      bfv8 af  = ((const bfv8*)sw_s)[gg * 8 + ((ks * 4 + q4) ^ (gg & 7))];
      bfv8 bf0 = ((const bfv8*)fx_s)[d0 * 8 + ((ks * 4 + q4) ^ (d0 & 7))];
      bfv8 bf1 = ((const bfv8*)fx_s)[d1 * 8 + ((ks * 4 + q4) ^ (d1 & 7))];
      acc0 = __builtin_amdgcn_mfma_f32_16x16x32_bf16(af, bf0, acc0, 0, 0, 0);
      acc1 = __builtin_amdgcn_mfma_f32_16x16x32_bf16(af, bf1, acc1, 0, 0, 0);
    }
  }
  if (w < 2) npart[w][lane] = nacc;
  __syncthreads();
  int bh = b * NHEADS + h;
  if (t < 64) normp[(size_t)split * (BB * NHEADS * GG) + bh * 64 + t] = npart[0][t] + npart[1][t];
  size_t base = ((size_t)split * (BB * NHEADS * GG) + bh * 64) * 32;
#pragma unroll
  for (int r = 0; r < 4; ++r) {
    int g = w * 16 + q4 * 4 + r;
    stp[base + (size_t)g * 32 + l15] = acc0[r];
    stp[base + (size_t)g * 32 + 16 + l15] = acc1[r];
  }
}

// ---------- fused attention + wo-column projection per (b,h) ----------
__global__ __launch_bounds__(256) void attn_wc_kernel(
    const float* __restrict__ stp, const float* __restrict__ normp,
    const float* __restrict__ wq, const float* __restrict__ wk,
    const float* __restrict__ wv, const float* __restrict__ wo,
    bf16* __restrict__ wct) {
  __shared__ float wqs[32 * 32], wks[32 * 32], wvs[32 * 32];
  __shared__ float st[GG][DHD + 1];
  __shared__ float qq[GG][DHD + 1], kk[GG][DHD + 1], vv[GG][DHD + 1];
  __shared__ float pm[GG][GG + 1];
  __shared__ float nrm[GG];
  int bh = blockIdx.x;
  int h2 = bh & 7, bq = bh >> 3;
  int t = threadIdx.x;
  ((float4*)wqs)[t] = ((const float4*)wq)[t];
  ((float4*)wks)[t] = ((const float4*)wk)[t];
  ((float4*)wvs)[t] = ((const float4*)wv)[t];
  float wol[DHD];                           // wo column c = t, loaded early
#pragma unroll
  for (int d = 0; d < DHD; ++d) wol[d] = wo[(size_t)(h2 * DHD + d) * CC + t];
  if (t < 64) {
    float ns = 0.f;
    for (int s = 0; s < SPLIT; ++s) ns += normp[(size_t)s * (BB * NHEADS * GG) + bh * 64 + t];
    nrm[t] = 1.0f / (ns + 1e-5f);
  }
  __syncthreads();
#pragma unroll
  for (int i = 0; i < 8; ++i) {
    int idx = t + i * 256;
    int g = idx >> 5, d = idx & 31;
    float a = 0.f;
    for (int s = 0; s < SPLIT; ++s)
      a += stp[((size_t)s * (BB * NHEADS * GG) + bh * 64 + g) * 32 + d];
    st[g][d] = a * nrm[g];
  }
  __syncthreads();
#pragma unroll
  for (int i = 0; i < 8; ++i) {
    int idx = t + i * 256;
    int g = idx >> 5, d = idx & 31;
    float aq = 0.f, ak = 0.f, av = 0.f;
#pragma unroll
    for (int c = 0; c < 32; ++c) {
      float sv = st[g][c];
      aq += sv * wqs[c * 32 + d];
      ak += sv * wks[c * 32 + d];
      av += sv * wvs[c * 32 + d];
    }
    qq[g][d] = aq; kk[g][d] = ak; vv[g][d] = av;
  }
  __syncthreads();
  {
    int g = t >> 2, sub = t & 3;
    float sc[16];
    float m = -1e30f;
    const float scale = 0.17677669529663687f;
#pragma unroll
    for (int jj = 0; jj < 16; ++jj) {
      int j = sub * 16 + jj;
      float a = 0.f;
#pragma unroll
      for (int d = 0; d < 32; ++d) a += qq[g][d] * kk[j][d];
      a *= scale;
      sc[jj] = a;
      m = fmaxf(m, a);
    }
    m = fmaxf(m, __shfl_xor(m, 1, 64));
    m = fmaxf(m, __shfl_xor(m, 2, 64));
    float ssum = 0.f;
#pragma unroll
    for (int jj = 0; jj < 16; ++jj) { sc[jj] = __expf(sc[jj] - m); ssum += sc[jj]; }
    ssum += __shfl_xor(ssum, 1, 64);
    ssum += __shfl_xor(ssum, 2, 64);
    float rs = 1.0f / ssum;
#pragma unroll
    for (int jj = 0; jj < 16; ++jj) pm[g][sub * 16 + jj] = sc[jj] * rs;
  }
  __syncthreads();
#pragma unroll
  for (int i = 0; i < 8; ++i) {            // PV -> qq (Q dead after scores)
    int idx = t + i * 256;
    int g = idx >> 5, d = idx & 31;
    float a = 0.f;
#pragma unroll
    for (int j = 0; j < GG; ++j) a += pm[g][j] * vv[j][d];
    qq[g][d] = a;
  }
  __syncthreads();
  // wc: wct[b][c][h*64+g] = sum_d ot[g][d] * wo[h*32+d][c], c = t
  bf16* dst = wct + ((size_t)bq * CC + t) * (NHEADS * GG) + h2 * GG;
#pragma unroll 4
  for (int g = 0; g < GG; ++g) {
    float a = 0.f;
#pragma unroll
    for (int d = 0; d < DHD; ++d) a += wol[d] * qq[g][d];
    dst[g] = f2b(a);
  }
}

// ---------- final LN3 + head: one wave per point, float4, no LDS/barrier ----------
__global__ __launch_bounds__(256) void head_kernel(const float* __restrict__ fx,
                                                   const float* __restrict__ w,
                                                   const float* __restrict__ b,
                                                   const float* __restrict__ wout,
                                                   const float* __restrict__ bout,
                                                   float* __restrict__ out) {
  int wid = threadIdx.x >> 6, lane = threadIdx.x & 63;
  int p = blockIdx.x * 4 + wid;
  float4 v = ((const float4*)(fx + (size_t)p * CC))[lane];
  float s = v.x + v.y + v.z + v.w;
  float sq = v.x * v.x + v.y * v.y + v.z * v.z + v.w * v.w;
#pragma unroll
  for (int off = 32; off > 0; off >>= 1) {
    s += __shfl_xor(s, off, 64);
    sq += __shfl_xor(sq, off, 64);
  }
  float mean = s * (1.0f / CC);
  float var = sq * (1.0f / CC) - mean * mean;
  float rstd = rsqrtf(var + 1e-5f);
  float4 wv = ((const float4*)w)[lane];
  float4 bv = ((const float4*)b)[lane];
  float xn0 = (v.x - mean) * rstd * wv.x + bv.x;
  float xn1 = (v.y - mean) * rstd * wv.y + bv.y;
  float xn2 = (v.z - mean) * rstd * wv.z + bv.z;
  float xn3 = (v.w - mean) * rstd * wv.w + bv.w;
  float4 w0 = ((const float4*)wout)[lane * 4 + 0];
  float4 w1 = ((const float4*)wout)[lane * 4 + 1];
  float4 w2 = ((const float4*)wout)[lane * 4 + 2];
  float4 w3 = ((const float4*)wout)[lane * 4 + 3];
  float4 o;
  o.x = xn0 * w0.x + xn1 * w1.x + xn2 * w2.x + xn3 * w3.x;
  o.y = xn0 * w0.y + xn1 * w1.y + xn2 * w2.y + xn3 * w3.y;
  o.z = xn0 * w0.z + xn1 * w1.z + xn2 * w2.z + xn3 * w3.z;
  o.w = xn0 * w0.w + xn1 * w1.w + xn2 * w2.w + xn3 * w3.w;
#pragma unroll
  for (int off = 32; off > 0; off >>= 1) {
    o.x += __shfl_xor(o.x, off, 64);
    o.y += __shfl_xor(o.y, off, 64);
    o.z += __shfl_xor(o.z, off, 64);
    o.w += __shfl_xor(o.w, off, 64);
  }
  if (lane == 0) {
    float4 bo4 = *((const float4*)bout);
    float4 r;
    r.x = o.x + bo4.x; r.y = o.y + bo4.y; r.z = o.z + bo4.z; r.w = o.w + bo4.w;
    ((float4*)out)[p] = r;
  }
}

extern "C" void kernel_launch(void* const* d_in, const int* in_sizes, int n_in,
                              void* d_out, int out_size, void* d_ws, size_t ws_size,
                              hipStream_t stream) {
  const float* fx_in      = (const float*)d_in[0];
  const float* ln1_w      = (const float*)d_in[1];
  const float* ln1_b      = (const float*)d_in[2];
  const float* convx_w    = (const float*)d_in[3];
  const float* convx_b    = (const float*)d_in[4];
  const float* convfx_w   = (const float*)d_in[5];
  const float* convfx_b   = (const float*)d_in[6];
  const float* slice_w    = (const float*)d_in[7];
  const float* slice_b    = (const float*)d_in[8];
  const float* temperature= (const float*)d_in[9];
  const float* wq         = (const float*)d_in[10];
  const float* wk         = (const float*)d_in[11];
  const float* wv         = (const float*)d_in[12];
  const float* wo         = (const float*)d_in[13];
  const float* bo         = (const float*)d_in[14];
  const float* ln2_w      = (const float*)d_in[15];
  const float* ln2_b      = (const float*)d_in[16];
  const float* w1         = (const float*)d_in[17];
  const float* b1         = (const float*)d_in[18];
  const float* w2         = (const float*)d_in[19];
  const float* b2         = (const float*)d_in[20];
  const float* ln3_w      = (const float*)d_in[21];
  const float* ln3_b      = (const float*)d_in[22];
  const float* w_out      = (const float*)d_in[23];
  const float* b_out      = (const float*)d_in[24];
  float* out = (float*)d_out;

  char* ws = (char*)d_ws;
  size_t off = 0;
  auto alloc = [&](size_t bytes) -> void* {
    void* p = ws + off;
    off += (bytes + 255) & ~(size_t)255;
    return p;
  };
  float* fx32  = (float*)alloc((size_t)BB * NN * CC * 4);    // 64 MiB
  bf16* xln    = (bf16*)alloc((size_t)BB * NN * CC * 2);     // 32 MiB
  char* uni    = (char*)alloc((size_t)BB * NN * 512 * 2 * 2);// xmid/fxmid/swb region
  bf16* xmid   = (bf16*)uni;
  bf16* fxmid  = (bf16*)(uni + (size_t)BB * NN * INNERC * 2);
  bf16* swb    = (bf16*)(uni + (size_t)2 * BB * NN * INNERC * 2);
  float* stp   = (float*)uni;                                // 8 MiB (aliases dead xmid)
  float* normp = (float*)(uni + (size_t)SPLIT * BB * NHEADS * GG * DHD * 4);
  bf16* wtx    = (bf16*)alloc((size_t)LL * 9 * CC * INNERC * 2);
  bf16* wtfx   = (bf16*)alloc((size_t)LL * 9 * CC * INNERC * 2);
  bf16* w1t    = (bf16*)alloc((size_t)LL * CC * HIDD * 2);
  bf16* w2t    = (bf16*)alloc((size_t)LL * HIDD * CC * 2);
  bf16* wct    = (bf16*)alloc((size_t)BB * CC * NHEADS * GG * 2);   // 1 MiB
  float* zbuf  = (float*)alloc(256);                          // zero pad for conv halo
  (void)ws_size; (void)in_sizes; (void)n_in; (void)out_size;

  hipMemsetAsync(zbuf, 0, 256, stream);

  transpose_cast_kernel<<<dim3(8, 8, LL * 9), 256, 0, stream>>>(convx_w, wtx, CC, INNERC);
  transpose_cast_kernel<<<dim3(8, 8, LL * 9), 256, 0, stream>>>(convfx_w, wtfx, CC, INNERC);
  transpose_cast_kernel<<<dim3(32, 8, LL), 256, 0, stream>>>(w1, w1t, CC, HIDD);
  transpose_cast_kernel<<<dim3(8, 32, LL), 256, 0, stream>>>(w2, w2t, HIDD, CC);

  hipMemcpyAsync(fx32, fx_in, (size_t)BB * NN * CC * sizeof(float),
                 hipMemcpyDeviceToDevice, stream);

  const int M = BB * NN;  // 65536
  ln_kernel<<<M / 4, 256, 0, stream>>>(fx32, ln1_w, ln1_b, xln);
  for (int i = 0; i < LL; ++i) {
    conv_mfma_kernel<<<BB * HH / 2, 512, 0, stream>>>(
        xln, wtfx + (size_t)i * 9 * CC * INNERC, convfx_b + i * INNERC, fxmid,
        (const float*)zbuf);
    conv_mfma_kernel<<<BB * HH / 2, 512, 0, stream>>>(
        xln, wtx + (size_t)i * 9 * CC * INNERC, convx_b + i * INNERC, xmid,
        (const float*)zbuf);
    slice_softmax_kernel<<<M / SSP, 256, 0, stream>>>(
        xmid, slice_w + i * DHD * GG, slice_b + i * GG, temperature + i * NHEADS, swb);
    slice_st_kernel<<<dim3(SPLIT, NHEADS, BB), 256, 0, stream>>>(fxmid, swb, stp, normp);
    attn_wc_kernel<<<BB * NHEADS, 256, 0, stream>>>(
        stp, normp, wq + i * DHD * DHD, wk + i * DHD * DHD, wv + i * DHD * DHD,
        wo + (size_t)i * INNERC * CC, wct);
    // fx += sw @ Wc + bo, then xln = ln2(fx)  (deslice + wo-proj + residual + LN fused)
    gemm_ln_kernel<<<dim3(NN / 128, BB), 512, 0, stream>>>(
        swb, wct, bo + i * CC, fx32, ln2_w + i * CC, ln2_b + i * CC, xln);
    // fx += mlp(xln)
    mlp_fused_kernel<<<M / 64, 512, 0, stream>>>(
        xln, w1t + (size_t)i * CC * HIDD, b1 + i * HIDD,
        w2t + (size_t)i * HIDD * CC, b2 + i * CC, fx32);
    if (i < LL - 1)
      ln_kernel<<<M / 4, 256, 0, stream>>>(fx32, ln1_w + (i + 1) * CC,
                                           ln1_b + (i + 1) * CC, xln);
  }
  head_kernel<<<M / 4, 256, 0, stream>>>(fx32, ln3_w, ln3_b, w_out, b_out, out);
}

// Round 12
// 2209.655 us; speedup vs baseline: 1.0834x; 1.0022x over previous
//
#include <hip/hip_runtime.h>
#include <hip/hip_bf16.h>

typedef __hip_bfloat16 bf16;
typedef __bf16 bfv8 __attribute__((ext_vector_type(8)));
typedef float f32x4 __attribute__((ext_vector_type(4)));

#define BB 4
#define HH 128
#define WWI 128
#define NN 16384      // HH*WWI
#define CC 256
#define LL 4
#define NHEADS 8
#define DHD 32
#define GG 64
#define INNERC 256    // NHEADS*DHD
#define HIDD 1024
#define SPLIT 32      // split-K blocks per (b,h) in slice_st
#define SSP 32        // points per block in slice_softmax (r12: 16->32)

__device__ __forceinline__ float b2f(bf16 x) { return __bfloat162float(x); }
__device__ __forceinline__ bf16 f2b(float x) { return __float2bfloat16(x); }
__device__ __forceinline__ float us2f(unsigned short v) {
  return __uint_as_float(((unsigned)v) << 16);
}
__device__ __forceinline__ unsigned short b2us(bf16 h) {
  union { bf16 b; unsigned short u; } c; c.b = h; return c.u;
}

// async global->LDS, 16B per lane; LDS dest = wave-uniform base + lane*16
__device__ __forceinline__ void async16(void* l, const void* g) {
  __builtin_amdgcn_global_load_lds(
      (const __attribute__((address_space(1))) void*)g,
      (__attribute__((address_space(3))) void*)l, 16, 0, 0);
}

__device__ __forceinline__ float wave_sum(float v) {
#pragma unroll
  for (int off = 32; off > 0; off >>= 1) v += __shfl_down(v, off, 64);
  return v;
}

__device__ __forceinline__ float gelu_exact(float x) {
  return 0.5f * x * (1.0f + erff(x * 0.70710678118654752f));
}

// ---------- batched transpose+cast: src fp32 [T][R][Cm] -> dst bf16 [T][Cm][R] ----------
__global__ void transpose_cast_kernel(const float* __restrict__ src, bf16* __restrict__ dst,
                                      int R, int Cm) {
  __shared__ float tile[32][33];
  int tb = blockIdx.z;
  const float* s = src + (size_t)tb * R * Cm;
  bf16* d = dst + (size_t)tb * R * Cm;
  int c0 = blockIdx.x * 32, r0 = blockIdx.y * 32;
  int tx = threadIdx.x & 31, ty = threadIdx.x >> 5;  // 32 x 8
  for (int rr = ty; rr < 32; rr += 8) {
    int r = r0 + rr, c = c0 + tx;
    tile[rr][tx] = (r < R && c < Cm) ? s[(size_t)r * Cm + c] : 0.f;
  }
  __syncthreads();
  for (int cc = ty; cc < 32; cc += 8) {
    int c = c0 + cc, r = r0 + tx;
    if (c < Cm && r < R) d[(size_t)c * R + r] = f2b(tile[tx][cc]);
  }
}

// ---------- LayerNorm (ln1): one wave per point, float4 loads, no LDS/barrier ----------
__global__ __launch_bounds__(256) void ln_kernel(const float* __restrict__ x,
                                                 const float* __restrict__ w,
                                                 const float* __restrict__ b,
                                                 bf16* __restrict__ out) {
  int wid = threadIdx.x >> 6, lane = threadIdx.x & 63;
  int p = blockIdx.x * 4 + wid;
  float4 v = ((const float4*)(x + (size_t)p * CC))[lane];
  float s = v.x + v.y + v.z + v.w;
  float sq = v.x * v.x + v.y * v.y + v.z * v.z + v.w * v.w;
#pragma unroll
  for (int off = 32; off > 0; off >>= 1) {
    s += __shfl_xor(s, off, 64);
    sq += __shfl_xor(sq, off, 64);
  }
  float mean = s * (1.0f / CC);
  float var = sq * (1.0f / CC) - mean * mean;
  float rstd = rsqrtf(var + 1e-5f);
  float4 wv = ((const float4*)w)[lane];
  float4 bv = ((const float4*)b)[lane];
  unsigned short o0 = b2us(f2b((v.x - mean) * rstd * wv.x + bv.x));
  unsigned short o1 = b2us(f2b((v.y - mean) * rstd * wv.y + bv.y));
  unsigned short o2 = b2us(f2b((v.z - mean) * rstd * wv.z + bv.z));
  unsigned short o3 = b2us(f2b((v.w - mean) * rstd * wv.w + bv.w));
  uint2 pk = make_uint2((unsigned)o0 | ((unsigned)o1 << 16),
                        (unsigned)o2 | ((unsigned)o3 << 16));
  ((uint2*)(out + (size_t)p * CC))[lane] = pk;
}

// ---------- 3x3 conv pair as implicit MFMA GEMM (r12: both weight sets, z-merged) ----------
// grid (256, 2): z selects {wtfx->fxmid, wtx->xmid}; second half overlaps first's ramp.
__global__ __launch_bounds__(512, 2) void conv_mfma_kernel(
    const bf16* __restrict__ xln,
    const bf16* __restrict__ wt0, const bf16* __restrict__ wt1,
    const float* __restrict__ bias0, const float* __restrict__ bias1,
    bf16* __restrict__ out0, bf16* __restrict__ out1,
    const float* __restrict__ zbuf) {
  __shared__ __align__(16) unsigned short As[4 * 130 * 64];   // 65 KiB (rows h0-1..h0+2)
  __shared__ __align__(16) unsigned short Bsm[2][256 * 64];   // 2 x 32 KiB
  int z = blockIdx.y;
  const bf16* wt = z ? wt1 : wt0;
  const float* bias = z ? bias1 : bias0;
  bf16* out = z ? out1 : out0;
  int bid = blockIdx.x;
  bid = (bid & 7) * 32 + (bid >> 3);        // XCD swizzle (256 = 8*32, bijective)
  int h0 = (bid & 63) * 2;                  // output row pair
  int b = bid >> 6;
  int t = threadIdx.x, lane = t & 63, wid = t >> 6;
  int r = wid & 1;                          // output row within pair
  int wn = (wid >> 1) * 64;                 // oc quarter
  int l15 = lane & 15, l4 = lane >> 4;
  int wu = t & ~63;                         // wave-uniform thread base
  f32x4 acc[8][4];
#pragma unroll
  for (int mi = 0; mi < 8; ++mi)
#pragma unroll
    for (int ni = 0; ni < 4; ++ni) acc[mi][ni] = (f32x4){0.f, 0.f, 0.f, 0.f};
  const bf16* xbase = xln + (size_t)b * NN * CC;

  auto stageB = [&](int buf, int tap, int q) {
#pragma unroll
    for (int k = 0; k < 4; ++k) {
      int u = t + k * 512;
      int n = u >> 3, jp = u & 7, j = jp ^ (n & 7);
      async16(&Bsm[buf][(size_t)(wu + k * 512) * 8],
              wt + ((size_t)(tap * 256 + n)) * 256 + q * 64 + j * 8);
    }
  };

  for (int q = 0; q < 4; ++q) {             // 64-channel K chunks
#pragma unroll
    for (int k = 0; k < 8; ++k) {
      int u = t + k * 512;
      int jp = u & 7, pc = u >> 3;
      int ar = pc / 130, cl = pc - ar * 130;
      int j = jp ^ (cl & 7);
      int gr = h0 + ar - 1, gc = cl - 1;
      const void* src =
          ((unsigned)gr < 128u && (unsigned)gc < 128u)
              ? (const void*)(xbase + ((size_t)(gr * WWI + gc)) * CC + q * 64 + j * 8)
              : (const void*)zbuf;
      async16(&As[(size_t)(wu + k * 512) * 8], src);
    }
    if (t < 64) {
      int u = t + 4096;
      int jp = u & 7, pc = u >> 3;
      int ar = pc / 130, cl = pc - ar * 130;
      int j = jp ^ (cl & 7);
      int gr = h0 + ar - 1, gc = cl - 1;
      const void* src =
          ((unsigned)gr < 128u && (unsigned)gc < 128u)
              ? (const void*)(xbase + ((size_t)(gr * WWI + gc)) * CC + q * 64 + j * 8)
              : (const void*)zbuf;
      async16(&As[(size_t)4096 * 8], src);
    }
    if (q == 0) stageB(0, 0, 0);
    __syncthreads();

    for (int tap = 0; tap < 9; ++tap) {
      int cur = (q * 9 + tap) & 1;
      if (tap < 8)      stageB(cur ^ 1, tap + 1, q);
      else if (q < 3)   stageB(cur ^ 1, 0, q + 1);
      int ky = tap / 3, kx = tap - ky * 3;
      const unsigned short* Bc = Bsm[cur];
#pragma unroll
      for (int s = 0; s < 2; ++s) {
        bfv8 af[8], bfr[4];
#pragma unroll
        for (int mi = 0; mi < 8; ++mi) {
          int cl = mi * 16 + l15 + kx;
          af[mi] = *(const bfv8*)(&As[((size_t)((ky + r) * 130 + cl)) * 64 +
                                      (((s * 4 + l4) ^ (cl & 7)) << 3)]);
        }
#pragma unroll
        for (int ni = 0; ni < 4; ++ni) {
          int rn = wn + ni * 16 + l15;
          bfr[ni] = *(const bfv8*)(&Bc[(size_t)rn * 64 + (((s * 4 + l4) ^ (rn & 7)) << 3)]);
        }
#pragma unroll
        for (int mi = 0; mi < 8; ++mi)
#pragma unroll
          for (int ni = 0; ni < 4; ++ni)
            acc[mi][ni] = __builtin_amdgcn_mfma_f32_16x16x32_bf16(af[mi], bfr[ni], acc[mi][ni], 0, 0, 0);
      }
      __syncthreads();
    }
  }
  int colB = wn + l15;
  int rowB = l4 * 4;
#pragma unroll
  for (int ni = 0; ni < 4; ++ni) {
    int oc = colB + ni * 16;
    float bv = bias[oc];
#pragma unroll
    for (int mi = 0; mi < 8; ++mi) {
#pragma unroll
      for (int rr = 0; rr < 4; ++rr) {
        int pix = mi * 16 + rowB + rr;
        out[((size_t)(b * NN + (h0 + r) * WWI + pix)) * CC + oc] = f2b(acc[mi][ni][rr] + bv);
      }
    }
  }
}

// ---------- fused deslice GEMM + residual + LN2 (unchanged) ----------
__global__ __launch_bounds__(512) void gemm_ln_kernel(
    const bf16* __restrict__ A, const bf16* __restrict__ BT,
    const float* __restrict__ bias, float* __restrict__ fx,
    const float* __restrict__ lw, const float* __restrict__ lb,
    bf16* __restrict__ xout) {
  __shared__ __align__(16) unsigned short As[128 * 64];   // 16 KiB
  __shared__ __align__(16) unsigned short Bs[256 * 64];   // 32 KiB
  int z = blockIdx.y;
  const bf16* Aa = A + (size_t)z * NN * 512;
  const bf16* Ba = BT + (size_t)z * 256 * 512;
  size_t fb = (size_t)z * NN * 256;
  int m0 = blockIdx.x * 128;
  int t = threadIdx.x, lane = t & 63, wid = t >> 6;
  int wm = (wid & 1) * 64, wn = (wid >> 1) * 64;
  int l15 = lane & 15, q4 = lane >> 4;
  int wu = t & ~63;
  f32x4 acc[4][4];
#pragma unroll
  for (int mi = 0; mi < 4; ++mi)
#pragma unroll
    for (int ni = 0; ni < 4; ++ni) acc[mi][ni] = (f32x4){0.f, 0.f, 0.f, 0.f};

  for (int kb = 0; kb < 512; kb += 64) {
    __syncthreads();
#pragma unroll
    for (int i = 0; i < 2; ++i) {          // A: 128 rows x 64k = 1024 units
      int u = t + i * 512;
      int row = u >> 3, jp = u & 7, j = jp ^ (row & 7);
      async16(&As[(size_t)(wu + i * 512) * 8], Aa + (size_t)(m0 + row) * 512 + kb + j * 8);
    }
#pragma unroll
    for (int i = 0; i < 4; ++i) {          // B: 256 rows x 64k = 2048 units
      int u = t + i * 512;
      int n = u >> 3, jp = u & 7, j = jp ^ (n & 7);
      async16(&Bs[(size_t)(wu + i * 512) * 8], Ba + (size_t)n * 512 + kb + j * 8);
    }
    __syncthreads();
#pragma unroll
    for (int s = 0; s < 2; ++s) {
      int kgrp = s * 4 + q4;
      bfv8 af[4], bfr[4];
#pragma unroll
      for (int mi = 0; mi < 4; ++mi) {
        int row = wm + mi * 16 + l15;
        af[mi] = *(const bfv8*)(&As[(size_t)row * 64 + ((kgrp ^ (row & 7)) << 3)]);
      }
#pragma unroll
      for (int ni = 0; ni < 4; ++ni) {
        int n = wn + ni * 16 + l15;
        bfr[ni] = *(const bfv8*)(&Bs[(size_t)n * 64 + ((kgrp ^ (n & 7)) << 3)]);
      }
#pragma unroll
      for (int mi = 0; mi < 4; ++mi)
#pragma unroll
        for (int ni = 0; ni < 4; ++ni)
          acc[mi][ni] = __builtin_amdgcn_mfma_f32_16x16x32_bf16(af[mi], bfr[ni], acc[mi][ni], 0, 0, 0);
    }
  }
  // ---- epilogue: v = fx + acc + bias; stats; ln2 -> xout ----
  __syncthreads();                          // all waves past As/Bs reads; alias As
  float* rs = (float*)As;                   // [4][128]
  float* rq = rs + 512;                     // [4][128]
  int cw = wid >> 1;
  int colB = wn + l15;
  float bv[4], lwv[4], lbv[4];
#pragma unroll
  for (int ni = 0; ni < 4; ++ni) {
    bv[ni] = bias[colB + ni * 16];
    lwv[ni] = lw[colB + ni * 16];
    lbv[ni] = lb[colB + ni * 16];
  }
  float vkeep[4][4][4];
#pragma unroll
  for (int mi = 0; mi < 4; ++mi) {
#pragma unroll
    for (int r = 0; r < 4; ++r) {
      int row = m0 + wm + mi * 16 + q4 * 4 + r;
      float s = 0.f, sq = 0.f;
#pragma unroll
      for (int ni = 0; ni < 4; ++ni) {
        size_t idx = fb + (size_t)row * 256 + colB + ni * 16;
        float v = fx[idx] + acc[mi][ni][r] + bv[ni];
        fx[idx] = v;
        vkeep[mi][r][ni] = v;
        s += v; sq += v * v;
      }
#pragma unroll
      for (int off = 1; off < 16; off <<= 1) {
        s += __shfl_xor(s, off, 64);
        sq += __shfl_xor(sq, off, 64);
      }
      if (l15 == 0) {
        int lrow = wm + mi * 16 + q4 * 4 + r;
        rs[cw * 128 + lrow] = s;
        rq[cw * 128 + lrow] = sq;
      }
    }
  }
  __syncthreads();
#pragma unroll
  for (int mi = 0; mi < 4; ++mi) {
#pragma unroll
    for (int r = 0; r < 4; ++r) {
      int lrow = wm + mi * 16 + q4 * 4 + r;
      float tot = rs[lrow] + rs[128 + lrow] + rs[256 + lrow] + rs[384 + lrow];
      float totq = rq[lrow] + rq[128 + lrow] + rq[256 + lrow] + rq[384 + lrow];
      float mean = tot * (1.0f / CC);
      float var = totq * (1.0f / CC) - mean * mean;
      float rstd = rsqrtf(var + 1e-5f);
      int row = m0 + lrow;
#pragma unroll
      for (int ni = 0; ni < 4; ++ni) {
        size_t idx = fb + (size_t)row * 256 + colB + ni * 16;
        float v = vkeep[mi][r][ni];         // from registers, no re-read
        xout[idx] = f2b((v - mean) * rstd * lwv[ni] + lbv[ni]);
      }
    }
  }
}

// ---------- fused MLP (r11, async16 staging): fx += gelu(xln@w1+b1)@w2+b2 ----------
__global__ __launch_bounds__(512, 4) void mlp_fused_kernel(
    const bf16* __restrict__ xln, const bf16* __restrict__ w1t,
    const float* __restrict__ b1, const bf16* __restrict__ w2t,
    const float* __restrict__ b2, float* __restrict__ fx) {
  __shared__ __align__(16) unsigned short As[64 * 256];   // 32 KiB (per-64 XOR swizzle)
  __shared__ __align__(16) bf16 Hs[64 * 128];             // 16 KiB
  __shared__ __align__(16) unsigned short Wb[256 * 64];   // 32 KiB weight staging
  int m0 = blockIdx.x * 64;
  int t = threadIdx.x, lane = t & 63, wid = t >> 6;       // wid 0..7
  int l15 = lane & 15, q4 = lane >> 4;
  int wm2 = (wid & 1) * 32, wn2 = (wid >> 1) * 32;
  int wm = (wid & 1) * 32, wn = (wid >> 1) * 64;
  int wu = t & ~63;

  const unsigned short* xg = (const unsigned short*)xln + (size_t)m0 * 256;
#pragma unroll
  for (int i = 0; i < 4; ++i) {
    int u = t + i * 512;
    int row = u >> 5;
    int su = (u & ~7) | ((u & 7) ^ (row & 7));
    async16(&As[(size_t)(wu + i * 512) * 8], xg + (size_t)su * 8);
  }

  f32x4 accO[2][4];
#pragma unroll
  for (int mi = 0; mi < 2; ++mi)
#pragma unroll
    for (int ni = 0; ni < 4; ++ni) accO[mi][ni] = (f32x4){0.f, 0.f, 0.f, 0.f};

  for (int j = 0; j < 8; ++j) {           // hidden chunks of 128
    int hbase = j * 128;
    f32x4 acc2[2][2];
#pragma unroll
    for (int mi = 0; mi < 2; ++mi)
#pragma unroll
      for (int nj = 0; nj < 2; ++nj) acc2[mi][nj] = (f32x4){0.f, 0.f, 0.f, 0.f};
    for (int kb = 0; kb < 4; ++kb) {
      __syncthreads();
#pragma unroll
      for (int i = 0; i < 2; ++i) {       // stage W1T chunk [128 n][64 k] = 16 KiB
        int u = t + i * 512;
        int n = u >> 3, j2 = (u & 7) ^ (n & 7);
        async16(&Wb[(size_t)(wu + i * 512) * 8],
                w1t + (size_t)(hbase + n) * 256 + kb * 64 + j2 * 8);
      }
      __syncthreads();
#pragma unroll
      for (int ks = 0; ks < 2; ++ks) {
        int kgrp = ks * 4 + q4;
        bfv8 af[2], bfr[2];
#pragma unroll
        for (int mi = 0; mi < 2; ++mi) {
          int row = wm2 + mi * 16 + l15;
          af[mi] = *(const bfv8*)(&As[row * 256 + kb * 64 + ((kgrp ^ (row & 7)) << 3)]);
        }
#pragma unroll
        for (int nj = 0; nj < 2; ++nj) {
          int n = wn2 + nj * 16 + l15;
          bfr[nj] = *(const bfv8*)(&Wb[n * 64 + ((kgrp ^ (n & 7)) << 3)]);
        }
#pragma unroll
        for (int mi = 0; mi < 2; ++mi)
#pragma unroll
          for (int nj = 0; nj < 2; ++nj)
            acc2[mi][nj] = __builtin_amdgcn_mfma_f32_16x16x32_bf16(af[mi], bfr[nj], acc2[mi][nj], 0, 0, 0);
      }
    }
#pragma unroll
    for (int nj = 0; nj < 2; ++nj) {
      int coln = wn2 + nj * 16 + l15;
      float bv = b1[hbase + coln];
      int half = coln >> 6, sub = (coln >> 3) & 7, lo = coln & 7;
#pragma unroll
      for (int mi = 0; mi < 2; ++mi) {
#pragma unroll
        for (int r = 0; r < 4; ++r) {
          int row = wm2 + mi * 16 + q4 * 4 + r;
          float v = acc2[mi][nj][r] + bv;
          Hs[row * 128 + half * 64 + (((sub ^ (row & 7)) << 3) + lo)] = f2b(gelu_exact(v));
        }
      }
    }
    for (int kb2 = 0; kb2 < 2; ++kb2) {
      __syncthreads();                    // Hs visible (first iter); Wb free
#pragma unroll
      for (int i = 0; i < 4; ++i) {       // stage W2T chunk [256 n][64 k] = 32 KiB
        int u = t + i * 512;
        int n = u >> 3, j2 = (u & 7) ^ (n & 7);
        async16(&Wb[(size_t)(wu + i * 512) * 8],
                w2t + (size_t)n * 1024 + hbase + kb2 * 64 + j2 * 8);
      }
      __syncthreads();
#pragma unroll
      for (int ks = 0; ks < 2; ++ks) {
        int kgrp = ks * 4 + q4;
        bfv8 af[2], bfr[4];
#pragma unroll
        for (int mi = 0; mi < 2; ++mi) {
          int row = wm + mi * 16 + l15;
          af[mi] = *(const bfv8*)(&Hs[row * 128 + kb2 * 64 + ((kgrp ^ (row & 7)) << 3)]);
        }
#pragma unroll
        for (int ni = 0; ni < 4; ++ni) {
          int n = wn + ni * 16 + l15;
          bfr[ni] = *(const bfv8*)(&Wb[n * 64 + ((kgrp ^ (n & 7)) << 3)]);
        }
#pragma unroll
        for (int mi = 0; mi < 2; ++mi)
#pragma unroll
          for (int ni = 0; ni < 4; ++ni)
            accO[mi][ni] = __builtin_amdgcn_mfma_f32_16x16x32_bf16(af[mi], bfr[ni], accO[mi][ni], 0, 0, 0);
      }
    }
  }
  // ---- epilogue: fx += accO + b2 ----
#pragma unroll
  for (int ni = 0; ni < 4; ++ni) {
    int col = wn + ni * 16 + l15;
    float bv = b2[col];
#pragma unroll
    for (int mi = 0; mi < 2; ++mi) {
#pragma unroll
      for (int r = 0; r < 4; ++r) {
        int row = m0 + wm + mi * 16 + q4 * 4 + r;
        fx[(size_t)row * 256 + col] += accO[mi][ni][r] + bv;
      }
    }
  }
}

// ---------- slice logits + softmax: weights in registers; SSP=32 pts/block ----------
__global__ __launch_bounds__(256) void slice_softmax_kernel(
    const bf16* __restrict__ xmid, const float* __restrict__ sw_w,
    const float* __restrict__ sw_b, const float* __restrict__ temp,
    bf16* __restrict__ swout) {
  __shared__ float xm[SSP][256];    // 32 KiB
  int p0 = blockIdx.x * SSP;
  int t = threadIdx.x;
  int g = t & 63, pq = t >> 6;
  float wreg[32];
#pragma unroll
  for (int d = 0; d < 32; ++d) wreg[d] = sw_w[d * 64 + g];   // coalesced per d
  float bg = sw_b[g];
  float rt[8];
#pragma unroll
  for (int h = 0; h < 8; ++h) rt[h] = 1.0f / fminf(fmaxf(temp[h], 0.1f), 5.0f);
  const unsigned short* xg = (const unsigned short*)xmid + (size_t)p0 * 256;
#pragma unroll
  for (int i2 = t; i2 < SSP * 32; i2 += 256) {
    uint4 v = ((const uint4*)xg)[i2];
    int p = i2 >> 5, c = (i2 & 31) << 3;
    xm[p][c + 0] = us2f((unsigned short)(v.x & 0xffff));
    xm[p][c + 1] = us2f((unsigned short)(v.x >> 16));
    xm[p][c + 2] = us2f((unsigned short)(v.y & 0xffff));
    xm[p][c + 3] = us2f((unsigned short)(v.y >> 16));
    xm[p][c + 4] = us2f((unsigned short)(v.z & 0xffff));
    xm[p][c + 5] = us2f((unsigned short)(v.z >> 16));
    xm[p][c + 6] = us2f((unsigned short)(v.w & 0xffff));
    xm[p][c + 7] = us2f((unsigned short)(v.w >> 16));
  }
  __syncthreads();
  for (int pp2 = 0; pp2 < SSP / 4; ++pp2) {
    int p = pp2 * 4 + pq;
#pragma unroll
    for (int h = 0; h < NHEADS; ++h) {
      float acc = bg;
      const float* xr = &xm[p][h * 32];
#pragma unroll
      for (int d = 0; d < 32; ++d) acc += xr[d] * wreg[d];
      float logit = acc * rt[h];
      float m = logit;
#pragma unroll
      for (int off = 32; off > 0; off >>= 1) m = fmaxf(m, __shfl_xor(m, off, 64));
      float e = __expf(logit - m);
      float s = e;
#pragma unroll
      for (int off = 32; off > 0; off >>= 1) s += __shfl_xor(s, off, 64);
      swout[(size_t)(p0 + p) * 512 + h * 64 + g] = f2b(e / s);
    }
  }
}

// ---------- slice reduce as split-K MFMA outer product (unchanged) ----------
__global__ __launch_bounds__(256) void slice_st_kernel(
    const bf16* __restrict__ fxmid, const bf16* __restrict__ sw,
    float* __restrict__ stp, float* __restrict__ normp) {
  __shared__ __align__(16) unsigned short sw_s[64 * 64];
  __shared__ __align__(16) unsigned short fx_s[32 * 64];
  __shared__ float npart[2][64];
  int split = blockIdx.x, h = blockIdx.y, b = blockIdx.z;
  int t = threadIdx.x, w = t >> 6, lane = t & 63;
  int l15 = lane & 15, q4 = lane >> 4;
  int ns0 = split * (NN / SPLIT);
  const int NT = (NN / SPLIT) / 64;
  f32x4 acc0 = {0.f, 0.f, 0.f, 0.f}, acc1 = {0.f, 0.f, 0.f, 0.f};
  float nacc = 0.f;
  const unsigned short* swg = (const unsigned short*)sw + (size_t)b * NN * 512 + h * 64;
  const unsigned short* fxg = (const unsigned short*)fxmid + (size_t)b * NN * 256 + h * 32;

  for (int kt = 0; kt < NT; ++kt) {
    int n0 = ns0 + kt * 64;
    __syncthreads();
    if (w < 2) {
      int g = lane;
#pragma unroll
      for (int i = 0; i < 4; ++i) {
        int j = w + 2 * i;
        const unsigned short* p = swg + (size_t)(n0 + j * 8) * 512 + g;
        unsigned short v0 = p[0],     v1 = p[512],  v2 = p[1024], v3 = p[1536];
        unsigned short v4 = p[2048],  v5 = p[2560], v6 = p[3072], v7 = p[3584];
        nacc += us2f(v0) + us2f(v1) + us2f(v2) + us2f(v3) +
                us2f(v4) + us2f(v5) + us2f(v6) + us2f(v7);
        uint4 pk = make_uint4((unsigned)v0 | ((unsigned)v1 << 16),
                              (unsigned)v2 | ((unsigned)v3 << 16),
                              (unsigned)v4 | ((unsigned)v5 << 16),
                              (unsigned)v6 | ((unsigned)v7 << 16));
        ((uint4*)sw_s)[g * 8 + (j ^ (g & 7))] = pk;
      }
    } else {
      int d = lane & 31, nh = lane >> 5, w3 = w - 2;
#pragma unroll
      for (int i = 0; i < 2; ++i) {
        int nbase = (w3 * 2 + i) * 16 + nh * 8;
        const unsigned short* p = fxg + (size_t)(n0 + nbase) * 256 + d;
        unsigned short v0 = p[0],    v1 = p[256],  v2 = p[512],  v3 = p[768];
        unsigned short v4 = p[1024], v5 = p[1280], v6 = p[1536], v7 = p[1792];
        uint4 pk = make_uint4((unsigned)v0 | ((unsigned)v1 << 16),
                              (unsigned)v2 | ((unsigned)v3 << 16),
                              (unsigned)v4 | ((unsigned)v5 << 16),
                              (unsigned)v6 | ((unsigned)v7 << 16));
        int u = nbase >> 3;
        ((uint4*)fx_s)[d * 8 + (u ^ (d & 7))] = pk;
      }
    }
    __syncthreads();
    int gg = w * 16 + l15;
    int d0 = l15, d1 = 16 + l15;
#pragma unroll
    for (int ks = 0; ks < 2; ++ks) {
      bfv8 af  = ((const bfv8*)sw_s)[gg * 8 + ((ks * 4 + q4) ^ (gg & 7))];
      bfv8 bf0 = ((const bfv8*)fx_s)[d0 * 8 + ((ks * 4 + q4) ^ (d0 & 7))];
      bfv8 bf1 = ((const bfv8*)fx_s)[d1 * 8 + ((ks * 4 + q4) ^ (d1 & 7))];
      acc0 = __builtin_amdgcn_mfma_f32_16x16x32_bf16(af, bf0, acc0, 0, 0, 0);
      acc1 = __builtin_amdgcn_mfma_f32_16x16x32_bf16(af, bf1, acc1, 0, 0, 0);
    }
  }
  if (w < 2) npart[w][lane] = nacc;
  __syncthreads();
  int bh = b * NHEADS + h;
  if (t < 64) normp[(size_t)split * (BB * NHEADS * GG) + bh * 64 + t] = npart[0][t] + npart[1][t];
  size_t base = ((size_t)split * (BB * NHEADS * GG) + bh * 64) * 32;
#pragma unroll
  for (int r = 0; r < 4; ++r) {
    int g = w * 16 + q4 * 4 + r;
    stp[base + (size_t)g * 32 + l15] = acc0[r];
    stp[base + (size_t)g * 32 + 16 + l15] = acc1[r];
  }
}

// ---------- fused attention + wo-column projection per (b,h) ----------
__global__ __launch_bounds__(256) void attn_wc_kernel(
    const float* __restrict__ stp, const float* __restrict__ normp,
    const float* __restrict__ wq, const float* __restrict__ wk,
    const float* __restrict__ wv, const float* __restrict__ wo,
    bf16* __restrict__ wct) {
  __shared__ float wqs[32 * 32], wks[32 * 32], wvs[32 * 32];
  __shared__ float st[GG][DHD + 1];
  __shared__ float qq[GG][DHD + 1], kk[GG][DHD + 1], vv[GG][DHD + 1];
  __shared__ float pm[GG][GG + 1];
  __shared__ float nrm[GG];
  int bh = blockIdx.x;
  int h2 = bh & 7, bq = bh >> 3;
  int t = threadIdx.x;
  ((float4*)wqs)[t] = ((const float4*)wq)[t];
  ((float4*)wks)[t] = ((const float4*)wk)[t];
  ((float4*)wvs)[t] = ((const float4*)wv)[t];
  float wol[DHD];                           // wo column c = t, loaded early
#pragma unroll
  for (int d = 0; d < DHD; ++d) wol[d] = wo[(size_t)(h2 * DHD + d) * CC + t];
  if (t < 64) {
    float ns = 0.f;
    for (int s = 0; s < SPLIT; ++s) ns += normp[(size_t)s * (BB * NHEADS * GG) + bh * 64 + t];
    nrm[t] = 1.0f / (ns + 1e-5f);
  }
  __syncthreads();
#pragma unroll
  for (int i = 0; i < 8; ++i) {
    int idx = t + i * 256;
    int g = idx >> 5, d = idx & 31;
    float a = 0.f;
    for (int s = 0; s < SPLIT; ++s)
      a += stp[((size_t)s * (BB * NHEADS * GG) + bh * 64 + g) * 32 + d];
    st[g][d] = a * nrm[g];
  }
  __syncthreads();
#pragma unroll
  for (int i = 0; i < 8; ++i) {
    int idx = t + i * 256;
    int g = idx >> 5, d = idx & 31;
    float aq = 0.f, ak = 0.f, av = 0.f;
#pragma unroll
    for (int c = 0; c < 32; ++c) {
      float sv = st[g][c];
      aq += sv * wqs[c * 32 + d];
      ak += sv * wks[c * 32 + d];
      av += sv * wvs[c * 32 + d];
    }
    qq[g][d] = aq; kk[g][d] = ak; vv[g][d] = av;
  }
  __syncthreads();
  {
    int g = t >> 2, sub = t & 3;
    float sc[16];
    float m = -1e30f;
    const float scale = 0.17677669529663687f;
#pragma unroll
    for (int jj = 0; jj < 16; ++jj) {
      int j = sub * 16 + jj;
      float a = 0.f;
#pragma unroll
      for (int d = 0; d < 32; ++d) a += qq[g][d] * kk[j][d];
      a *= scale;
      sc[jj] = a;
      m = fmaxf(m, a);
    }
    m = fmaxf(m, __shfl_xor(m, 1, 64));
    m = fmaxf(m, __shfl_xor(m, 2, 64));
    float ssum = 0.f;
#pragma unroll
    for (int jj = 0; jj < 16; ++jj) { sc[jj] = __expf(sc[jj] - m); ssum += sc[jj]; }
    ssum += __shfl_xor(ssum, 1, 64);
    ssum += __shfl_xor(ssum, 2, 64);
    float rs = 1.0f / ssum;
#pragma unroll
    for (int jj = 0; jj < 16; ++jj) pm[g][sub * 16 + jj] = sc[jj] * rs;
  }
  __syncthreads();
#pragma unroll
  for (int i = 0; i < 8; ++i) {            // PV -> qq (Q dead after scores)
    int idx = t + i * 256;
    int g = idx >> 5, d = idx & 31;
    float a = 0.f;
#pragma unroll
    for (int j = 0; j < GG; ++j) a += pm[g][j] * vv[j][d];
    qq[g][d] = a;
  }
  __syncthreads();
  // wc: wct[b][c][h*64+g] = sum_d ot[g][d] * wo[h*32+d][c], c = t
  bf16* dst = wct + ((size_t)bq * CC + t) * (NHEADS * GG) + h2 * GG;
#pragma unroll 4
  for (int g = 0; g < GG; ++g) {
    float a = 0.f;
#pragma unroll
    for (int d = 0; d < DHD; ++d) a += wol[d] * qq[g][d];
    dst[g] = f2b(a);
  }
}

// ---------- final LN3 + head: one wave per point, float4, no LDS/barrier ----------
__global__ __launch_bounds__(256) void head_kernel(const float* __restrict__ fx,
                                                   const float* __restrict__ w,
                                                   const float* __restrict__ b,
                                                   const float* __restrict__ wout,
                                                   const float* __restrict__ bout,
                                                   float* __restrict__ out) {
  int wid = threadIdx.x >> 6, lane = threadIdx.x & 63;
  int p = blockIdx.x * 4 + wid;
  float4 v = ((const float4*)(fx + (size_t)p * CC))[lane];
  float s = v.x + v.y + v.z + v.w;
  float sq = v.x * v.x + v.y * v.y + v.z * v.z + v.w * v.w;
#pragma unroll
  for (int off = 32; off > 0; off >>= 1) {
    s += __shfl_xor(s, off, 64);
    sq += __shfl_xor(sq, off, 64);
  }
  float mean = s * (1.0f / CC);
  float var = sq * (1.0f / CC) - mean * mean;
  float rstd = rsqrtf(var + 1e-5f);
  float4 wv = ((const float4*)w)[lane];
  float4 bv = ((const float4*)b)[lane];
  float xn0 = (v.x - mean) * rstd * wv.x + bv.x;
  float xn1 = (v.y - mean) * rstd * wv.y + bv.y;
  float xn2 = (v.z - mean) * rstd * wv.z + bv.z;
  float xn3 = (v.w - mean) * rstd * wv.w + bv.w;
  float4 w0 = ((const float4*)wout)[lane * 4 + 0];
  float4 w1 = ((const float4*)wout)[lane * 4 + 1];
  float4 w2 = ((const float4*)wout)[lane * 4 + 2];
  float4 w3 = ((const float4*)wout)[lane * 4 + 3];
  float4 o;
  o.x = xn0 * w0.x + xn1 * w1.x + xn2 * w2.x + xn3 * w3.x;
  o.y = xn0 * w0.y + xn1 * w1.y + xn2 * w2.y + xn3 * w3.y;
  o.z = xn0 * w0.z + xn1 * w1.z + xn2 * w2.z + xn3 * w3.z;
  o.w = xn0 * w0.w + xn1 * w1.w + xn2 * w2.w + xn3 * w3.w;
#pragma unroll
  for (int off = 32; off > 0; off >>= 1) {
    o.x += __shfl_xor(o.x, off, 64);
    o.y += __shfl_xor(o.y, off, 64);
    o.z += __shfl_xor(o.z, off, 64);
    o.w += __shfl_xor(o.w, off, 64);
  }
  if (lane == 0) {
    float4 bo4 = *((const float4*)bout);
    float4 r;
    r.x = o.x + bo4.x; r.y = o.y + bo4.y; r.z = o.z + bo4.z; r.w = o.w + bo4.w;
    ((float4*)out)[p] = r;
  }
}

extern "C" void kernel_launch(void* const* d_in, const int* in_sizes, int n_in,
                              void* d_out, int out_size, void* d_ws, size_t ws_size,
                              hipStream_t stream) {
  const float* fx_in      = (const float*)d_in[0];
  const float* ln1_w      = (const float*)d_in[1];
  const float* ln1_b      = (const float*)d_in[2];
  const float* convx_w    = (const float*)d_in[3];
  const float* convx_b    = (const float*)d_in[4];
  const float* convfx_w   = (const float*)d_in[5];
  const float* convfx_b   = (const float*)d_in[6];
  const float* slice_w    = (const float*)d_in[7];
  const float* slice_b    = (const float*)d_in[8];
  const float* temperature= (const float*)d_in[9];
  const float* wq         = (const float*)d_in[10];
  const float* wk         = (const float*)d_in[11];
  const float* wv         = (const float*)d_in[12];
  const float* wo         = (const float*)d_in[13];
  const float* bo         = (const float*)d_in[14];
  const float* ln2_w      = (const float*)d_in[15];
  const float* ln2_b      = (const float*)d_in[16];
  const float* w1         = (const float*)d_in[17];
  const float* b1         = (const float*)d_in[18];
  const float* w2         = (const float*)d_in[19];
  const float* b2         = (const float*)d_in[20];
  const float* ln3_w      = (const float*)d_in[21];
  const float* ln3_b      = (const float*)d_in[22];
  const float* w_out      = (const float*)d_in[23];
  const float* b_out      = (const float*)d_in[24];
  float* out = (float*)d_out;

  char* ws = (char*)d_ws;
  size_t off = 0;
  auto alloc = [&](size_t bytes) -> void* {
    void* p = ws + off;
    off += (bytes + 255) & ~(size_t)255;
    return p;
  };
  float* fx32  = (float*)alloc((size_t)BB * NN * CC * 4);    // 64 MiB
  bf16* xln    = (bf16*)alloc((size_t)BB * NN * CC * 2);     // 32 MiB
  char* uni    = (char*)alloc((size_t)BB * NN * 512 * 2 * 2);// xmid/fxmid/swb region
  bf16* xmid   = (bf16*)uni;
  bf16* fxmid  = (bf16*)(uni + (size_t)BB * NN * INNERC * 2);
  bf16* swb    = (bf16*)(uni + (size_t)2 * BB * NN * INNERC * 2);
  float* stp   = (float*)uni;                                // 8 MiB (aliases dead xmid)
  float* normp = (float*)(uni + (size_t)SPLIT * BB * NHEADS * GG * DHD * 4);
  bf16* wtx    = (bf16*)alloc((size_t)LL * 9 * CC * INNERC * 2);
  bf16* wtfx   = (bf16*)alloc((size_t)LL * 9 * CC * INNERC * 2);
  bf16* w1t    = (bf16*)alloc((size_t)LL * CC * HIDD * 2);
  bf16* w2t    = (bf16*)alloc((size_t)LL * HIDD * CC * 2);
  bf16* wct    = (bf16*)alloc((size_t)BB * CC * NHEADS * GG * 2);   // 1 MiB
  float* zbuf  = (float*)alloc(256);                          // zero pad for conv halo
  (void)ws_size; (void)in_sizes; (void)n_in; (void)out_size;

  hipMemsetAsync(zbuf, 0, 256, stream);

  transpose_cast_kernel<<<dim3(8, 8, LL * 9), 256, 0, stream>>>(convx_w, wtx, CC, INNERC);
  transpose_cast_kernel<<<dim3(8, 8, LL * 9), 256, 0, stream>>>(convfx_w, wtfx, CC, INNERC);
  transpose_cast_kernel<<<dim3(32, 8, LL), 256, 0, stream>>>(w1, w1t, CC, HIDD);
  transpose_cast_kernel<<<dim3(8, 32, LL), 256, 0, stream>>>(w2, w2t, HIDD, CC);

  hipMemcpyAsync(fx32, fx_in, (size_t)BB * NN * CC * sizeof(float),
                 hipMemcpyDeviceToDevice, stream);

  const int M = BB * NN;  // 65536
  ln_kernel<<<M / 4, 256, 0, stream>>>(fx32, ln1_w, ln1_b, xln);
  for (int i = 0; i < LL; ++i) {
    // both convs in one dispatch: z=0 -> fxmid (wtfx), z=1 -> xmid (wtx)
    conv_mfma_kernel<<<dim3(BB * HH / 2, 2), 512, 0, stream>>>(
        xln,
        wtfx + (size_t)i * 9 * CC * INNERC, wtx + (size_t)i * 9 * CC * INNERC,
        convfx_b + i * INNERC, convx_b + i * INNERC,
        fxmid, xmid, (const float*)zbuf);
    slice_softmax_kernel<<<M / SSP, 256, 0, stream>>>(
        xmid, slice_w + i * DHD * GG, slice_b + i * GG, temperature + i * NHEADS, swb);
    slice_st_kernel<<<dim3(SPLIT, NHEADS, BB), 256, 0, stream>>>(fxmid, swb, stp, normp);
    attn_wc_kernel<<<BB * NHEADS, 256, 0, stream>>>(
        stp, normp, wq + i * DHD * DHD, wk + i * DHD * DHD, wv + i * DHD * DHD,
        wo + (size_t)i * INNERC * CC, wct);
    // fx += sw @ Wc + bo, then xln = ln2(fx)  (deslice + wo-proj + residual + LN fused)
    gemm_ln_kernel<<<dim3(NN / 128, BB), 512, 0, stream>>>(
        swb, wct, bo + i * CC, fx32, ln2_w + i * CC, ln2_b + i * CC, xln);
    // fx += mlp(xln)
    mlp_fused_kernel<<<M / 64, 512, 0, stream>>>(
        xln, w1t + (size_t)i * CC * HIDD, b1 + i * HIDD,
        w2t + (size_t)i * HIDD * CC, b2 + i * CC, fx32);
    if (i < LL - 1)
      ln_kernel<<<M / 4, 256, 0, stream>>>(fx32, ln1_w + (i + 1) * CC,
                                           ln1_b + (i + 1) * CC, xln);
  }
  head_kernel<<<M / 4, 256, 0, stream>>>(fx32, ln3_w, ln3_b, w_out, b_out, out);
}